// Round 5
// baseline (599.818 us; speedup 1.0000x reference)
//
#include <hip/hip_runtime.h>
#include <hip/hip_bf16.h>
#include <math.h>

// Problem sizes (fixed)
#define NROW    4096
#define DPROJ   1024
#define LDHB    1408         // 1024 + 256 + 64 + pad
#define HEAD_V  20003
#define TAIL_V  10000
#define HEAD_VP 20224        // 79*256
#define TAIL1_P 10240        // 40*256
#define TAIL_VP 10112        // 79*128 (tails 2,3 on 128-tile kernel)
#define NBH     79           // head col-blocks (256 wide)
#define NBT1    40           // tail1 col-blocks (256 wide)
#define NBT     79           // tail2/3 col-blocks (128 wide)

typedef short short8 __attribute__((ext_vector_type(8)));
typedef float f32x4  __attribute__((ext_vector_type(4)));

__device__ __forceinline__ ushort f2bf(float f) {           // RNE f32 -> bf16
    unsigned u = __builtin_bit_cast(unsigned, f);
    return (ushort)((u + 0x7FFFu + ((u >> 16) & 1u)) >> 16);
}
__device__ __forceinline__ float bf2f(ushort u) {
    unsigned x = (unsigned)u << 16;
    return __builtin_bit_cast(float, x);
}

#define GLOAD16(gp, lp) __builtin_amdgcn_global_load_lds(                     \
    (const __attribute__((address_space(1))) void*)(gp),                      \
    (__attribute__((address_space(3))) void*)(lp), 16, 0, 0)

// ---------------------------------------------------------------------------
// cast hidden f32 -> bf16  (4096x1024)
// ---------------------------------------------------------------------------
__global__ void cast_hidden_k(const float* __restrict__ h, ushort* __restrict__ hb) {
    int i = (blockIdx.x * 256 + threadIdx.x) * 4;
    float4 v = *(const float4*)(h + i);
    ushort4 o = {f2bf(v.x), f2bf(v.y), f2bf(v.z), f2bf(v.w)};
    *(ushort4*)(hb + i) = o;
}

// ---------------------------------------------------------------------------
// transpose-cast proj concat -> pbT [1408][1024] bf16 (row = out col, K-contig)
// ---------------------------------------------------------------------------
__global__ void cast_transpose_proj(const float* __restrict__ p0, const float* __restrict__ p1,
                                    const float* __restrict__ p2, const float* __restrict__ p3,
                                    ushort* __restrict__ pbT) {
    __shared__ float tile[64][65];
    const int t  = threadIdx.x;
    const int kb = blockIdx.x * 64;
    const int cb = blockIdx.y * 64;
    for (int p = 0; p < 4; ++p) {
        int kl = p * 16 + (t >> 4);
        int c4 = (t & 15) * 4;
        int k  = kb + kl;
        for (int j = 0; j < 4; ++j) {
            int c = cb + c4 + j;
            float v = 0.f;
            if      (c < 1024) v = p0[(size_t)k * 1024 + c];
            else if (c < 1280) v = p1[(size_t)k * 256  + (c - 1024)];
            else if (c < 1344) v = p2[(size_t)k * 64   + (c - 1280)];
            else if (c < 1360) v = p3[(size_t)k * 16   + (c - 1344)];
            tile[kl][c4 + j] = v;
        }
    }
    __syncthreads();
    for (int p = 0; p < 4; ++p) {
        int cl = p * 16 + (t >> 4);
        int k4 = (t & 15) * 4;
        ushort4 o = {f2bf(tile[k4 + 0][cl]), f2bf(tile[k4 + 1][cl]),
                     f2bf(tile[k4 + 2][cl]), f2bf(tile[k4 + 3][cl])};
        *(ushort4*)(pbT + (size_t)(cb + cl) * 1024 + kb + k4) = o;
    }
}

// ---------------------------------------------------------------------------
// cast head weight: [w0 (20000) | cluster_w (3) | zeros] -> WH [20224][1024]
// ---------------------------------------------------------------------------
__global__ void cast_head_w(const float* __restrict__ w0, const float* __restrict__ cw,
                            ushort* __restrict__ dst) {
    const int row = blockIdx.x;
    const int c   = threadIdx.x * 4;
    float4 v = {0.f, 0.f, 0.f, 0.f};
    if (row < 20000)      v = *(const float4*)(w0 + (size_t)row * 1024 + c);
    else if (row < 20003) v = *(const float4*)(cw + (size_t)(row - 20000) * 1024 + c);
    ushort4 o = {f2bf(v.x), f2bf(v.y), f2bf(v.z), f2bf(v.w)};
    *(ushort4*)(dst + (size_t)row * 1024 + c) = o;
}

// ---------------------------------------------------------------------------
// cast tail weight with row pad + K pad: src [rows_real][kin] -> dst [rows_pad][KOUT]
// ---------------------------------------------------------------------------
template<int KOUT>
__global__ void cast_tail_w(const float* __restrict__ src, ushort* __restrict__ dst,
                            int rows_real, int kin, int rows_pad) {
    int idx = blockIdx.x * 256 + threadIdx.x;
    const int n = rows_pad * KOUT;
    if (idx >= n) return;
    int r = idx / KOUT, k = idx - r * KOUT;
    float v = (r < rows_real && k < kin) ? src[(size_t)r * kin + k] : 0.f;
    dst[idx] = f2bf(v);
}

// ---------------------------------------------------------------------------
// Proj GEMM: Hb[4096][1408] = hb @ pbT^T  (m97-style 128x128, unchanged)
// ---------------------------------------------------------------------------
__global__ __launch_bounds__(256) void proj_gemm_mfma(const ushort* __restrict__ A,
                                                      const ushort* __restrict__ B,
                                                      ushort* __restrict__ C) {
    __shared__ ushort As[128 * 32];
    __shared__ ushort Bs[128 * 32];
    const int t  = threadIdx.x;
    const int wv = t >> 6, l = t & 63, lr = l & 15, lh = l >> 4;
    const int wr = wv >> 1, wc = wv & 1;
    const int rb = blockIdx.x * 128, cb = blockIdx.y * 128;
    f32x4 acc[4][4] = {};
    for (int k0 = 0; k0 < DPROJ; k0 += 32) {
        __syncthreads();
        #pragma unroll
        for (int is = 0; is < 2; ++is) {
            int rr = (t >> 2) + is * 64;
            GLOAD16(A + (size_t)(rb + rr) * DPROJ + k0 + (t & 3) * 8,
                    (char*)As + wv * 1024 + is * 4096);
            GLOAD16(B + (size_t)(cb + rr) * DPROJ + k0 + (t & 3) * 8,
                    (char*)Bs + wv * 1024 + is * 4096);
        }
        __syncthreads();
        short8 af[4], bf[4];
        #pragma unroll
        for (int m = 0; m < 4; ++m)
            af[m] = *(const short8*)(As + (wr * 64 + m * 16 + lr) * 32 + lh * 8);
        #pragma unroll
        for (int n = 0; n < 4; ++n)
            bf[n] = *(const short8*)(Bs + (wc * 64 + n * 16 + lr) * 32 + lh * 8);
        #pragma unroll
        for (int m = 0; m < 4; ++m)
            #pragma unroll
            for (int n = 0; n < 4; ++n)
                acc[m][n] = __builtin_amdgcn_mfma_f32_16x16x32_bf16(af[m], bf[n], acc[m][n], 0, 0, 0);
    }
    #pragma unroll
    for (int m = 0; m < 4; ++m)
        #pragma unroll
        for (int n = 0; n < 4; ++n)
            #pragma unroll
            for (int r = 0; r < 4; ++r) {
                int rl = wr * 64 + m * 16 + lh * 4 + r;
                int cl = wc * 64 + n * 16 + lr;
                C[(size_t)(rb + rl) * LDHB + cb + cl] = f2bf(acc[m][n][r]);
            }
}

// ---------------------------------------------------------------------------
// 256x256-tile, BK=64, 512-thr, 4 fine phases/K-tile (m201-style), 2-buf LDS
// (128 KB), T2 XOR-swizzle (elem ^= (row&7)<<3), all 8 stage-loads of tile
// kt+1 issued at ph0, per-wave vmcnt(0) only at tile boundary, raw barriers
// + setprio around each 16-MFMA cluster. Epilogue: exp(logit+bias) row-sums.
// ---------------------------------------------------------------------------
template<int K>
__global__ __launch_bounds__(512, 2) void gemm_sumexp_8ph(
        const ushort* __restrict__ A, int lda,
        const ushort* __restrict__ B,
        const float* __restrict__ bias, const float* __restrict__ biasx,
        int splitB, int vocab,
        float* __restrict__ partial, int nCB, int gridM) {
    extern __shared__ ushort lds[];     // 2 bufs x (A[256][64] + B[256][64])
    const int t  = threadIdx.x;
    const int wv = t >> 6, l = t & 63, lr = l & 15, lh = l >> 4;
    const int wr = wv >> 2, wc = wv & 3;             // 2M x 4N waves
    const int cpx = gridDim.x >> 3;                  // XCD swizzle (grid%8==0)
    const int bid = blockIdx.x;
    const int swz = (bid & 7) * cpx + (bid >> 3);
    const int bm = swz % gridM, bn = swz / gridM;
    const int rb = bm * 256, cb = bn * 256;
    constexpr int NT = K / 64;

    const int srow = t >> 3;                         // 0..63 (row within pass)
    const int scol = (t & 7) * 8;                    // elem chunk within row
    // stage one full K-tile: 4 half-tiles, 8 global_load_lds per wave.
    // LDS dest wave-linear; SOURCE col pre-inverse-swizzled (rule #21).
    auto stage = [&](int kt, int buf) {
        const int k0 = kt * 64;
        #pragma unroll
        for (int h = 0; h < 2; ++h)
            #pragma unroll
            for (int j = 0; j < 2; ++j) {
                int row = h * 128 + j * 64 + srow;
                int csw = scol ^ ((row & 7) << 3);
                GLOAD16(A + (size_t)(rb + row) * lda + k0 + csw,
                        (char*)lds + buf * 65536 + h * 16384 + j * 8192 + wv * 1024);
            }
        #pragma unroll
        for (int h = 0; h < 2; ++h)
            #pragma unroll
            for (int j = 0; j < 2; ++j) {
                int row = h * 128 + j * 64 + srow;
                int csw = scol ^ ((row & 7) << 3);
                GLOAD16(B + (size_t)(cb + row) * K + k0 + csw,
                        (char*)lds + buf * 65536 + 32768 + h * 16384 + j * 8192 + wv * 1024);
            }
    };

    short8 af[4], bf[4];
    f32x4 acc[8][4] = {};
    auto rdA = [&](int buf, int mh, int kk) {        // 4 swizzled ds_read_b128
        #pragma unroll
        for (int m = 0; m < 4; ++m) {
            int row  = wr * 128 + (mh * 4 + m) * 16 + lr;
            int elem = (kk * 32 + lh * 8) ^ ((row & 7) << 3);
            af[m] = *(const short8*)(lds + buf * 32768 + row * 64 + elem);
        }
    };
    auto rdB = [&](int buf, int kk) {
        #pragma unroll
        for (int n = 0; n < 4; ++n) {
            int row  = wc * 64 + n * 16 + lr;
            int elem = (kk * 32 + lh * 8) ^ ((row & 7) << 3);
            bf[n] = *(const short8*)(lds + buf * 32768 + 16384 + row * 64 + elem);
        }
    };
    auto mfma16 = [&](int mh) {
        __builtin_amdgcn_s_setprio(1);
        #pragma unroll
        for (int m = 0; m < 4; ++m)
            #pragma unroll
            for (int n = 0; n < 4; ++n)
                acc[mh * 4 + m][n] = __builtin_amdgcn_mfma_f32_16x16x32_bf16(
                    af[m], bf[n], acc[mh * 4 + m][n], 0, 0, 0);
        __builtin_amdgcn_s_setprio(0);
    };

    // prologue
    stage(0, 0);
    asm volatile("s_waitcnt vmcnt(0)" ::: "memory");
    __builtin_amdgcn_s_barrier();

    for (int kt = 0; kt < NT; ++kt) {
        const int buf = kt & 1;
        const bool hn = (kt + 1 < NT);
        // ph0: A(m0-3,kk0) + B(kk0) reads; issue ALL next-tile stages
        rdA(buf, 0, 0); rdB(buf, 0);
        if (hn) stage(kt + 1, buf ^ 1);
        __builtin_amdgcn_s_barrier();
        mfma16(0);
        __builtin_amdgcn_s_barrier();
        // ph1: A(m4-7,kk0)
        rdA(buf, 1, 0);
        __builtin_amdgcn_s_barrier();
        mfma16(1);
        __builtin_amdgcn_s_barrier();
        // ph2: A(m0-3,kk1) + B(kk1)
        rdA(buf, 0, 1); rdB(buf, 1);
        __builtin_amdgcn_s_barrier();
        mfma16(0);
        __builtin_amdgcn_s_barrier();
        // ph3: A(m4-7,kk1); boundary vmcnt after own MFMA work
        rdA(buf, 1, 1);
        __builtin_amdgcn_s_barrier();
        mfma16(1);
        if (hn) asm volatile("s_waitcnt vmcnt(0)" ::: "memory");
        __builtin_amdgcn_s_barrier();
    }

    // epilogue: exp(logit+bias), per-row sums; staging LDS dead -> red[4][256]
    float* red = (float*)lds;
    #pragma unroll
    for (int m = 0; m < 8; ++m)
        #pragma unroll
        for (int q = 0; q < 4; ++q) {
            float s = 0.f;
            #pragma unroll
            for (int n = 0; n < 4; ++n) {
                int col = cb + wc * 64 + n * 16 + lr;
                if (col < vocab) {
                    float bv = (col < splitB) ? bias[col] : biasx[col - splitB];
                    s += expf(acc[m][n][q] + bv);
                }
            }
            #pragma unroll
            for (int off = 1; off < 16; off <<= 1) s += __shfl_xor(s, off);
            if (lr == 0) red[wc * 256 + wr * 128 + m * 16 + lh * 4 + q] = s;
        }
    __syncthreads();
    if (t < 256)
        partial[(size_t)(rb + t) * nCB + bn] =
            red[t] + red[256 + t] + red[512 + t] + red[768 + t];
}

// ---------------------------------------------------------------------------
// 128x128 m97-style GEMM + sum-exp (tails 2,3 only)
// ---------------------------------------------------------------------------
template<int K>
__global__ __launch_bounds__(256) void gemm_sumexp_bf(
        const ushort* __restrict__ A,
        const ushort* __restrict__ B,
        const float* __restrict__ bias,
        int vocab, float* __restrict__ partial, int nCB) {
    __shared__ ushort As[128 * 32];
    __shared__ ushort Bs[128 * 32];
    __shared__ float  red[2][128];
    const int t  = threadIdx.x;
    const int wv = t >> 6, l = t & 63, lr = l & 15, lh = l >> 4;
    const int wr = wv >> 1, wc = wv & 1;
    const int rb = blockIdx.x * 128, cb = blockIdx.y * 128;
    f32x4 acc[4][4] = {};
    for (int k0 = 0; k0 < K; k0 += 32) {
        __syncthreads();
        #pragma unroll
        for (int is = 0; is < 2; ++is) {
            int rr = (t >> 2) + is * 64;
            GLOAD16(A + (size_t)(rb + rr) * LDHB + k0 + (t & 3) * 8,
                    (char*)As + wv * 1024 + is * 4096);
            GLOAD16(B + (size_t)(cb + rr) * K + k0 + (t & 3) * 8,
                    (char*)Bs + wv * 1024 + is * 4096);
        }
        __syncthreads();
        short8 af[4], bf[4];
        #pragma unroll
        for (int m = 0; m < 4; ++m)
            af[m] = *(const short8*)(As + (wr * 64 + m * 16 + lr) * 32 + lh * 8);
        #pragma unroll
        for (int n = 0; n < 4; ++n)
            bf[n] = *(const short8*)(Bs + (wc * 64 + n * 16 + lr) * 32 + lh * 8);
        #pragma unroll
        for (int m = 0; m < 4; ++m)
            #pragma unroll
            for (int n = 0; n < 4; ++n)
                acc[m][n] = __builtin_amdgcn_mfma_f32_16x16x32_bf16(af[m], bf[n], acc[m][n], 0, 0, 0);
    }
    float rs[4][4];
    #pragma unroll
    for (int m = 0; m < 4; ++m)
        #pragma unroll
        for (int r = 0; r < 4; ++r) {
            float s = 0.f;
            #pragma unroll
            for (int n = 0; n < 4; ++n) {
                int col = cb + wc * 64 + n * 16 + lr;
                if (col < vocab) s += expf(acc[m][n][r] + bias[col]);
            }
            rs[m][r] = s;
        }
    #pragma unroll
    for (int m = 0; m < 4; ++m)
        #pragma unroll
        for (int r = 0; r < 4; ++r) {
            #pragma unroll
            for (int off = 1; off < 16; off <<= 1)
                rs[m][r] += __shfl_xor(rs[m][r], off);
            if (lr == 0) red[wc][wr * 64 + m * 16 + lh * 4 + r] = rs[m][r];
        }
    __syncthreads();
    if (t < 128)
        partial[(size_t)(rb + t) * nCB + blockIdx.y] = red[0][t] + red[1][t];
}

// ---------------------------------------------------------------------------
// Finalize: one wave per row — gather target/cluster logits, assemble NLL.
// ---------------------------------------------------------------------------
__global__ void pals_finalize(const ushort* __restrict__ Hb,
                              const int* __restrict__ target,
                              const float* __restrict__ w0, const float* __restrict__ b0,
                              const float* __restrict__ w1, const float* __restrict__ b1,
                              const float* __restrict__ w2, const float* __restrict__ b2,
                              const float* __restrict__ w3, const float* __restrict__ b3,
                              const float* __restrict__ cw, const float* __restrict__ cbv,
                              const float* __restrict__ pH,
                              const float* __restrict__ pT1,
                              const float* __restrict__ pT2,
                              const float* __restrict__ pT3,
                              float* __restrict__ out) {
    const int wave = threadIdx.x >> 6;
    const int lane = threadIdx.x & 63;
    const int row  = blockIdx.x * 4 + wave;
    if (row >= NROW) return;
    const int t = target[row];
    const ushort* Hrow = Hb + (size_t)row * LDHB;

    float s = 0.f;
    for (int c = lane; c < NBH; c += 64) s += pH[(size_t)row * NBH + c];
    #pragma unroll
    for (int off = 32; off; off >>= 1) s += __shfl_xor(s, off);
    const float logSh = logf(s);

    float nll;
    if (t < 20000) {
        const float* wr0 = w0 + (size_t)t * 1024;
        float d = 0.f;
        for (int k = lane * 4; k < 1024; k += 256) {
            ushort4 a = *(const ushort4*)(Hrow + k);
            float4  b = *(const float4*)(wr0 + k);
            d += bf2f(a.x) * b.x + bf2f(a.y) * b.y + bf2f(a.z) * b.z + bf2f(a.w) * b.w;
        }
        #pragma unroll
        for (int off = 32; off; off >>= 1) d += __shfl_xor(d, off);
        nll = -(d + b0[t] - logSh);
    } else {
        const int i  = (t - 20000) / 10000 + 1;        // 1..3
        const int ci = 3 - i;                           // head_lp[:, -i] quirk
        const float* cwr = cw + (size_t)ci * 1024;
        float d = 0.f;
        for (int k = lane * 4; k < 1024; k += 256) {
            ushort4 a = *(const ushort4*)(Hrow + k);
            float4  b = *(const float4*)(cwr + k);
            d += bf2f(a.x) * b.x + bf2f(a.y) * b.y + bf2f(a.z) * b.z + bf2f(a.w) * b.w;
        }
        #pragma unroll
        for (int off = 32; off; off >>= 1) d += __shfl_xor(d, off);
        const float logit_c = d + cbv[ci];

        const int dl   = 1024 >> (2 * i);               // 256, 64, 16
        const int hoff = (i == 1) ? 1024 : (i == 2) ? 1280 : 1344;
        const float* wi = (i == 1) ? w1 : (i == 2) ? w2 : w3;
        const float* bi = (i == 1) ? b1 : (i == 2) ? b2 : b3;
        const float* pT = (i == 1) ? pT1 : (i == 2) ? pT2 : pT3;
        const int nbi  = (i == 1) ? NBT1 : NBT;
        const int tt = t - (20000 + (i - 1) * 10000);

        float dt = 0.f;
        const ushort* Hi = Hrow + hoff;
        for (int k = lane; k < dl; k += 64) dt += bf2f(Hi[k]) * wi[(size_t)tt * dl + k];
        #pragma unroll
        for (int off = 32; off; off >>= 1) dt += __shfl_xor(dt, off);

        float st = 0.f;
        for (int c = lane; c < nbi; c += 64) st += pT[(size_t)row * nbi + c];
        #pragma unroll
        for (int off = 32; off; off >>= 1) st += __shfl_xor(st, off);

        nll = -((logit_c - logSh) + (dt + bi[tt] - logf(st)));
    }
    if (lane == 0) out[row] = nll;
}

// ---------------------------------------------------------------------------
extern "C" void kernel_launch(void* const* d_in, const int* in_sizes, int n_in,
                              void* d_out, int out_size, void* d_ws, size_t ws_size,
                              hipStream_t stream) {
    const float* hidden = (const float*)d_in[0];
    const int*   target = (const int*)  d_in[1];
    const float* proj0  = (const float*)d_in[2];
    const float* w0     = (const float*)d_in[3];
    const float* b0     = (const float*)d_in[4];
    const float* proj1  = (const float*)d_in[5];
    const float* w1     = (const float*)d_in[6];
    const float* b1     = (const float*)d_in[7];
    const float* proj2  = (const float*)d_in[8];
    const float* w2     = (const float*)d_in[9];
    const float* b2     = (const float*)d_in[10];
    const float* proj3  = (const float*)d_in[11];
    const float* w3     = (const float*)d_in[12];
    const float* b3     = (const float*)d_in[13];
    const float* cw     = (const float*)d_in[14];
    const float* cbv    = (const float*)d_in[15];

    ushort* hb  = (ushort*)d_ws;                         // [4096][1024]
    ushort* pbT = hb  + (size_t)NROW * DPROJ;            // [1408][1024]
    ushort* Hb  = pbT + (size_t)LDHB * DPROJ;            // [4096][1408]
    ushort* WH  = Hb  + (size_t)NROW * LDHB;             // [20224][1024]
    ushort* WT1 = WH  + (size_t)HEAD_VP * 1024;          // [10240][256]
    ushort* WT2 = WT1 + (size_t)TAIL1_P * 256;           // [10112][64]
    ushort* WT3 = WT2 + (size_t)TAIL_VP * 64;            // [10112][32]
    float*  pH  = (float*)(WT3 + (size_t)TAIL_VP * 32);  // [4096][79]
    float*  pT1 = pH  + (size_t)NROW * NBH;              // [4096][40]
    float*  pT2 = pT1 + (size_t)NROW * NBT1;             // [4096][79]
    float*  pT3 = pT2 + (size_t)NROW * NBT;              // [4096][79]

    dim3 blk(256);
    cast_hidden_k<<<dim3(NROW * DPROJ / 1024), blk, 0, stream>>>(hidden, hb);
    cast_transpose_proj<<<dim3(16, 22), blk, 0, stream>>>(proj0, proj1, proj2, proj3, pbT);
    cast_head_w<<<dim3(HEAD_VP), blk, 0, stream>>>(w0, cw, WH);
    cast_tail_w<256><<<dim3(TAIL1_P), blk, 0, stream>>>(w1, WT1, TAIL_V, 256, TAIL1_P);
    cast_tail_w<64><<<dim3((TAIL_VP * 64 + 255) / 256), blk, 0, stream>>>(w2, WT2, TAIL_V, 64, TAIL_VP);
    cast_tail_w<32><<<dim3((TAIL_VP * 32 + 255) / 256), blk, 0, stream>>>(w3, WT3, TAIL_V, 16, TAIL_VP);

    proj_gemm_mfma<<<dim3(32, 11), blk, 0, stream>>>(hb, pbT, Hb);

    // head: 16 x 79 = 1264 blocks (%8==0), 128 KB dynamic LDS
    gemm_sumexp_8ph<1024><<<dim3(16 * NBH), dim3(512), 131072, stream>>>(
        Hb, LDHB, WH, b0, cbv, 20000, HEAD_V, pH, NBH, 16);
    // tail1: 16 x 40 = 640 blocks
    gemm_sumexp_8ph<256><<<dim3(16 * NBT1), dim3(512), 131072, stream>>>(
        Hb + 1024, LDHB, WT1, b1, b1, TAIL_V, TAIL_V, pT1, NBT1, 16);
    // tails 2,3 on the 128-tile kernel
    gemm_sumexp_bf<64><<<dim3(32, NBT), blk, 0, stream>>>(
        Hb + 1280, WT2, b2, TAIL_V, pT2, NBT);
    gemm_sumexp_bf<32><<<dim3(32, NBT), blk, 0, stream>>>(
        Hb + 1344, WT3, b3, TAIL_V, pT3, NBT);

    pals_finalize<<<dim3(NROW / 4), blk, 0, stream>>>(
        Hb, target, w0, b0, w1, b1, w2, b2, w3, b3, cw, cbv,
        pH, pT1, pT2, pT3, (float*)d_out);
}

// Round 6
// 583.415 us; speedup vs baseline: 1.0281x; 1.0281x over previous
//
#include <hip/hip_runtime.h>
#include <hip/hip_bf16.h>
#include <math.h>

// Problem sizes (fixed)
#define NROW    4096
#define DPROJ   1024
#define LDHB    1408         // 1024 + 256 + 64 + pad
#define HEAD_V  20003
#define TAIL_V  10000
#define HEAD_VP 20224        // 79*256
#define TAIL1_P 10240        // 40*256
#define TAIL_VP 10112        // 79*128 (tails 2,3 on 128-tile kernel)
#define NBH     79           // head col-blocks (256 wide)
#define NBT1    40           // tail1 col-blocks (256 wide)
#define NBT     79           // tail2/3 col-blocks (128 wide)

typedef short short8 __attribute__((ext_vector_type(8)));
typedef float f32x4  __attribute__((ext_vector_type(4)));

__device__ __forceinline__ ushort f2bf(float f) {           // RNE f32 -> bf16
    unsigned u = __builtin_bit_cast(unsigned, f);
    return (ushort)((u + 0x7FFFu + ((u >> 16) & 1u)) >> 16);
}
__device__ __forceinline__ float bf2f(ushort u) {
    unsigned x = (unsigned)u << 16;
    return __builtin_bit_cast(float, x);
}

#define GLOAD16(gp, lp) __builtin_amdgcn_global_load_lds(                     \
    (const __attribute__((address_space(1))) void*)(gp),                      \
    (__attribute__((address_space(3))) void*)(lp), 16, 0, 0)

// ---------------------------------------------------------------------------
// cast hidden f32 -> bf16  (4096x1024)
// ---------------------------------------------------------------------------
__global__ void cast_hidden_k(const float* __restrict__ h, ushort* __restrict__ hb) {
    int i = (blockIdx.x * 256 + threadIdx.x) * 4;
    float4 v = *(const float4*)(h + i);
    ushort4 o = {f2bf(v.x), f2bf(v.y), f2bf(v.z), f2bf(v.w)};
    *(ushort4*)(hb + i) = o;
}

// ---------------------------------------------------------------------------
// transpose-cast proj concat -> pbT [1408][1024] bf16 (row = out col, K-contig)
// ---------------------------------------------------------------------------
__global__ void cast_transpose_proj(const float* __restrict__ p0, const float* __restrict__ p1,
                                    const float* __restrict__ p2, const float* __restrict__ p3,
                                    ushort* __restrict__ pbT) {
    __shared__ float tile[64][65];
    const int t  = threadIdx.x;
    const int kb = blockIdx.x * 64;
    const int cb = blockIdx.y * 64;
    for (int p = 0; p < 4; ++p) {
        int kl = p * 16 + (t >> 4);
        int c4 = (t & 15) * 4;
        int k  = kb + kl;
        for (int j = 0; j < 4; ++j) {
            int c = cb + c4 + j;
            float v = 0.f;
            if      (c < 1024) v = p0[(size_t)k * 1024 + c];
            else if (c < 1280) v = p1[(size_t)k * 256  + (c - 1024)];
            else if (c < 1344) v = p2[(size_t)k * 64   + (c - 1280)];
            else if (c < 1360) v = p3[(size_t)k * 16   + (c - 1344)];
            tile[kl][c4 + j] = v;
        }
    }
    __syncthreads();
    for (int p = 0; p < 4; ++p) {
        int cl = p * 16 + (t >> 4);
        int k4 = (t & 15) * 4;
        ushort4 o = {f2bf(tile[k4 + 0][cl]), f2bf(tile[k4 + 1][cl]),
                     f2bf(tile[k4 + 2][cl]), f2bf(tile[k4 + 3][cl])};
        *(ushort4*)(pbT + (size_t)(cb + cl) * 1024 + kb + k4) = o;
    }
}

// ---------------------------------------------------------------------------
// cast head weight: [w0 (20000) | cluster_w (3) | zeros] -> WH [20224][1024]
// ---------------------------------------------------------------------------
__global__ void cast_head_w(const float* __restrict__ w0, const float* __restrict__ cw,
                            ushort* __restrict__ dst) {
    const int row = blockIdx.x;
    const int c   = threadIdx.x * 4;
    float4 v = {0.f, 0.f, 0.f, 0.f};
    if (row < 20000)      v = *(const float4*)(w0 + (size_t)row * 1024 + c);
    else if (row < 20003) v = *(const float4*)(cw + (size_t)(row - 20000) * 1024 + c);
    ushort4 o = {f2bf(v.x), f2bf(v.y), f2bf(v.z), f2bf(v.w)};
    *(ushort4*)(dst + (size_t)row * 1024 + c) = o;
}

// ---------------------------------------------------------------------------
// cast tail weight with row pad + K pad: src [rows_real][kin] -> dst [rows_pad][KOUT]
// ---------------------------------------------------------------------------
template<int KOUT>
__global__ void cast_tail_w(const float* __restrict__ src, ushort* __restrict__ dst,
                            int rows_real, int kin, int rows_pad) {
    int idx = blockIdx.x * 256 + threadIdx.x;
    const int n = rows_pad * KOUT;
    if (idx >= n) return;
    int r = idx / KOUT, k = idx - r * KOUT;
    float v = (r < rows_real && k < kin) ? src[(size_t)r * kin + k] : 0.f;
    dst[idx] = f2bf(v);
}

// ---------------------------------------------------------------------------
// Proj GEMM: Hb[4096][1408] = hb @ pbT^T  (m97-style 128x128, unchanged)
// ---------------------------------------------------------------------------
__global__ __launch_bounds__(256) void proj_gemm_mfma(const ushort* __restrict__ A,
                                                      const ushort* __restrict__ B,
                                                      ushort* __restrict__ C) {
    __shared__ ushort As[128 * 32];
    __shared__ ushort Bs[128 * 32];
    const int t  = threadIdx.x;
    const int wv = t >> 6, l = t & 63, lr = l & 15, lh = l >> 4;
    const int wr = wv >> 1, wc = wv & 1;
    const int rb = blockIdx.x * 128, cb = blockIdx.y * 128;
    f32x4 acc[4][4] = {};
    for (int k0 = 0; k0 < DPROJ; k0 += 32) {
        __syncthreads();
        #pragma unroll
        for (int is = 0; is < 2; ++is) {
            int rr = (t >> 2) + is * 64;
            GLOAD16(A + (size_t)(rb + rr) * DPROJ + k0 + (t & 3) * 8,
                    (char*)As + wv * 1024 + is * 4096);
            GLOAD16(B + (size_t)(cb + rr) * DPROJ + k0 + (t & 3) * 8,
                    (char*)Bs + wv * 1024 + is * 4096);
        }
        __syncthreads();
        short8 af[4], bf[4];
        #pragma unroll
        for (int m = 0; m < 4; ++m)
            af[m] = *(const short8*)(As + (wr * 64 + m * 16 + lr) * 32 + lh * 8);
        #pragma unroll
        for (int n = 0; n < 4; ++n)
            bf[n] = *(const short8*)(Bs + (wc * 64 + n * 16 + lr) * 32 + lh * 8);
        #pragma unroll
        for (int m = 0; m < 4; ++m)
            #pragma unroll
            for (int n = 0; n < 4; ++n)
                acc[m][n] = __builtin_amdgcn_mfma_f32_16x16x32_bf16(af[m], bf[n], acc[m][n], 0, 0, 0);
    }
    #pragma unroll
    for (int m = 0; m < 4; ++m)
        #pragma unroll
        for (int n = 0; n < 4; ++n)
            #pragma unroll
            for (int r = 0; r < 4; ++r) {
                int rl = wr * 64 + m * 16 + lh * 4 + r;
                int cl = wc * 64 + n * 16 + lr;
                C[(size_t)(rb + rl) * LDHB + cb + cl] = f2bf(acc[m][n][r]);
            }
}

// ---------------------------------------------------------------------------
// 256x256 tile, BK=64, 512 thr, counted-vmcnt half-tile pipeline (T2+T3+T4+T5).
// LDS 128 KB: A[2][256][64] | B[2][256][64], XOR-swizzled (byte ^= (row&7)<<4).
// Per K-tile: 4 phases x 16 MFMA. Stage ONE half-tile (2 gloads) per phase:
//   ph0: Bh1(t+1)   ph1: Ah1(t+1)   ph2: Bh0(t+2)   ph3: Ah0(t+2)
// (each target buffer released >=1 phase earlier by barrier+lgkm discipline).
// Boundary wait = vmcnt(4): tile t+1 landed, t+2's 4 newest loads in flight.
// ---------------------------------------------------------------------------
template<int K>
__global__ __launch_bounds__(512, 2) void gemm_sumexp_t4(
        const ushort* __restrict__ A, int lda,
        const ushort* __restrict__ B,
        const float* __restrict__ bias, const float* __restrict__ biasx,
        int splitB, int vocab,
        float* __restrict__ partial, int nCB, int gridM) {
    extern __shared__ ushort lds[];
    const int t  = threadIdx.x;
    const int wv = t >> 6, l = t & 63, lr = l & 15, lh = l >> 4;
    const int wr = wv >> 2, wc = wv & 3;             // 2M x 4N waves
    const int cpx = gridDim.x >> 3;                  // XCD swizzle (grid%8==0)
    const int bid = blockIdx.x;
    const int swzb = (bid & 7) * cpx + (bid >> 3);
    const int bm = swzb % gridM, bn = swzb / gridM;
    const int rb = bm * 256, cb = bn * 256;
    constexpr int NT = K / 64;

    const int srow = t >> 3;                         // 0..63
    const int scol = (t & 7) * 8;
    const int csw  = scol ^ ((srow & 7) << 3);       // pre-inverse-swizzled src col

    // stage one 128-row half of A or B for K-tile kt (2 global_load_lds)
    auto stageA = [&](int h, int kt) {
        if (kt >= NT) return;
        const int buf = kt & 1;
        const int k0  = kt * 64;
        #pragma unroll
        for (int j = 0; j < 2; ++j) {
            int row = h * 128 + j * 64 + srow;
            GLOAD16(A + (size_t)(rb + row) * lda + k0 + csw,
                    (char*)lds + buf * 32768 + (h * 128 + j * 64 + wv * 8) * 128);
        }
    };
    auto stageB = [&](int h, int kt) {
        if (kt >= NT) return;
        const int buf = kt & 1;
        const int k0  = kt * 64;
        #pragma unroll
        for (int j = 0; j < 2; ++j) {
            int row = h * 128 + j * 64 + srow;
            GLOAD16(B + (size_t)(cb + row) * K + k0 + csw,
                    (char*)lds + 65536 + buf * 32768 + (h * 128 + j * 64 + wv * 8) * 128);
        }
    };

    short8 af[8], bf0[4], bf1[4];
    f32x4  acc[8][4] = {};
    auto rdA8 = [&](int buf, int mh) {               // A[mh half][kk0,kk1]
        #pragma unroll
        for (int m = 0; m < 4; ++m)
            #pragma unroll
            for (int kk = 0; kk < 2; ++kk) {
                int row  = wr * 128 + (mh * 4 + m) * 16 + lr;
                int elem = (kk * 32 + lh * 8) ^ ((row & 7) << 3);
                af[m * 2 + kk] = *(const short8*)(lds + buf * 16384 + row * 64 + elem);
            }
    };
    auto rdB4 = [&](int buf, int nh, short8* bf) {   // B[nh pair][kk0,kk1]
        #pragma unroll
        for (int n = 0; n < 2; ++n)
            #pragma unroll
            for (int kk = 0; kk < 2; ++kk) {
                int row  = wc * 64 + (nh * 2 + n) * 16 + lr;
                int elem = (kk * 32 + lh * 8) ^ ((row & 7) << 3);
                bf[n * 2 + kk] = *(const short8*)(lds + 32768 + buf * 16384 + row * 64 + elem);
            }
    };
    auto mf16 = [&](int mh, int nh, short8* bf) {    // 16 MFMA quadrant
        __builtin_amdgcn_s_setprio(1);
        #pragma unroll
        for (int m = 0; m < 4; ++m)
            #pragma unroll
            for (int n = 0; n < 2; ++n)
                #pragma unroll
                for (int kk = 0; kk < 2; ++kk)
                    acc[mh * 4 + m][nh * 2 + n] = __builtin_amdgcn_mfma_f32_16x16x32_bf16(
                        af[m * 2 + kk], bf[n * 2 + kk], acc[mh * 4 + m][nh * 2 + n], 0, 0, 0);
        __builtin_amdgcn_s_setprio(0);
    };

    // prologue: tile0 fully + tile1's h0 halves; wait so tile0 landed (4 in flight)
    stageB(0, 0); stageA(0, 0); stageB(1, 0); stageA(1, 0);
    stageB(0, 1); stageA(0, 1);
    if (NT > 1) asm volatile("s_waitcnt vmcnt(4)" ::: "memory");
    else        asm volatile("s_waitcnt vmcnt(0)" ::: "memory");
    __builtin_amdgcn_s_barrier();

    for (int kt = 0; kt < NT; ++kt) {
        const int buf = kt & 1;
        // ---- ph0: A[m0-3] + B[n0-1] reads; stage Bh1(kt+1)
        rdA8(buf, 0);
        rdB4(buf, 0, bf0);
        stageB(1, kt + 1);
        __builtin_amdgcn_s_barrier();
        asm volatile("s_waitcnt lgkmcnt(0)" ::: "memory");
        __builtin_amdgcn_sched_barrier(0);
        mf16(0, 0, bf0);
        __builtin_amdgcn_s_barrier();
        // ---- ph1: B[n2-3] reads; stage Ah1(kt+1)
        rdB4(buf, 1, bf1);
        stageA(1, kt + 1);
        __builtin_amdgcn_s_barrier();
        asm volatile("s_waitcnt lgkmcnt(0)" ::: "memory");
        __builtin_amdgcn_sched_barrier(0);
        mf16(0, 1, bf1);
        __builtin_amdgcn_s_barrier();
        // ---- ph2: A[m4-7] reads; stage Bh0(kt+2)
        rdA8(buf, 1);
        stageB(0, kt + 2);
        __builtin_amdgcn_s_barrier();
        asm volatile("s_waitcnt lgkmcnt(0)" ::: "memory");
        __builtin_amdgcn_sched_barrier(0);
        mf16(1, 1, bf1);
        __builtin_amdgcn_s_barrier();
        // ---- ph3: no ds reads; stage Ah0(kt+2); boundary counted-vmcnt
        stageA(0, kt + 2);
        mf16(1, 0, bf0);
        if (kt + 2 < NT)      asm volatile("s_waitcnt vmcnt(4)" ::: "memory");
        else if (kt + 1 < NT) asm volatile("s_waitcnt vmcnt(0)" ::: "memory");
        __builtin_amdgcn_s_barrier();
    }

    // epilogue: exp(logit+bias), per-row sums; staging LDS dead -> red[4][256]
    float* red = (float*)lds;
    #pragma unroll
    for (int m = 0; m < 8; ++m)
        #pragma unroll
        for (int q = 0; q < 4; ++q) {
            float s = 0.f;
            #pragma unroll
            for (int n = 0; n < 4; ++n) {
                int col = cb + wc * 64 + n * 16 + lr;
                if (col < vocab) {
                    float bv = (col < splitB) ? bias[col] : biasx[col - splitB];
                    s += expf(acc[m][n][q] + bv);
                }
            }
            #pragma unroll
            for (int off = 1; off < 16; off <<= 1) s += __shfl_xor(s, off);
            if (lr == 0) red[wc * 256 + wr * 128 + m * 16 + lh * 4 + q] = s;
        }
    __syncthreads();
    if (t < 256)
        partial[(size_t)(rb + t) * nCB + bn] =
            red[t] + red[256 + t] + red[512 + t] + red[768 + t];
}

// ---------------------------------------------------------------------------
// 128x128 m97-style GEMM + sum-exp (tails 2,3 only)
// ---------------------------------------------------------------------------
template<int K>
__global__ __launch_bounds__(256) void gemm_sumexp_bf(
        const ushort* __restrict__ A,
        const ushort* __restrict__ B,
        const float* __restrict__ bias,
        int vocab, float* __restrict__ partial, int nCB) {
    __shared__ ushort As[128 * 32];
    __shared__ ushort Bs[128 * 32];
    __shared__ float  red[2][128];
    const int t  = threadIdx.x;
    const int wv = t >> 6, l = t & 63, lr = l & 15, lh = l >> 4;
    const int wr = wv >> 1, wc = wv & 1;
    const int rb = blockIdx.x * 128, cb = blockIdx.y * 128;
    f32x4 acc[4][4] = {};
    for (int k0 = 0; k0 < K; k0 += 32) {
        __syncthreads();
        #pragma unroll
        for (int is = 0; is < 2; ++is) {
            int rr = (t >> 2) + is * 64;
            GLOAD16(A + (size_t)(rb + rr) * LDHB + k0 + (t & 3) * 8,
                    (char*)As + wv * 1024 + is * 4096);
            GLOAD16(B + (size_t)(cb + rr) * K + k0 + (t & 3) * 8,
                    (char*)Bs + wv * 1024 + is * 4096);
        }
        __syncthreads();
        short8 af[4], bf[4];
        #pragma unroll
        for (int m = 0; m < 4; ++m)
            af[m] = *(const short8*)(As + (wr * 64 + m * 16 + lr) * 32 + lh * 8);
        #pragma unroll
        for (int n = 0; n < 4; ++n)
            bf[n] = *(const short8*)(Bs + (wc * 64 + n * 16 + lr) * 32 + lh * 8);
        #pragma unroll
        for (int m = 0; m < 4; ++m)
            #pragma unroll
            for (int n = 0; n < 4; ++n)
                acc[m][n] = __builtin_amdgcn_mfma_f32_16x16x32_bf16(af[m], bf[n], acc[m][n], 0, 0, 0);
    }
    float rs[4][4];
    #pragma unroll
    for (int m = 0; m < 4; ++m)
        #pragma unroll
        for (int r = 0; r < 4; ++r) {
            float s = 0.f;
            #pragma unroll
            for (int n = 0; n < 4; ++n) {
                int col = cb + wc * 64 + n * 16 + lr;
                if (col < vocab) s += expf(acc[m][n][r] + bias[col]);
            }
            rs[m][r] = s;
        }
    #pragma unroll
    for (int m = 0; m < 4; ++m)
        #pragma unroll
        for (int r = 0; r < 4; ++r) {
            #pragma unroll
            for (int off = 1; off < 16; off <<= 1)
                rs[m][r] += __shfl_xor(rs[m][r], off);
            if (lr == 0) red[wc][wr * 64 + m * 16 + lh * 4 + r] = rs[m][r];
        }
    __syncthreads();
    if (t < 128)
        partial[(size_t)(rb + t) * nCB + blockIdx.y] = red[0][t] + red[1][t];
}

// ---------------------------------------------------------------------------
// Finalize: one wave per row — gather target/cluster logits, assemble NLL.
// ---------------------------------------------------------------------------
__global__ void pals_finalize(const ushort* __restrict__ Hb,
                              const int* __restrict__ target,
                              const float* __restrict__ w0, const float* __restrict__ b0,
                              const float* __restrict__ w1, const float* __restrict__ b1,
                              const float* __restrict__ w2, const float* __restrict__ b2,
                              const float* __restrict__ w3, const float* __restrict__ b3,
                              const float* __restrict__ cw, const float* __restrict__ cbv,
                              const float* __restrict__ pH,
                              const float* __restrict__ pT1,
                              const float* __restrict__ pT2,
                              const float* __restrict__ pT3,
                              float* __restrict__ out) {
    const int wave = threadIdx.x >> 6;
    const int lane = threadIdx.x & 63;
    const int row  = blockIdx.x * 4 + wave;
    if (row >= NROW) return;
    const int t = target[row];
    const ushort* Hrow = Hb + (size_t)row * LDHB;

    float s = 0.f;
    for (int c = lane; c < NBH; c += 64) s += pH[(size_t)row * NBH + c];
    #pragma unroll
    for (int off = 32; off; off >>= 1) s += __shfl_xor(s, off);
    const float logSh = logf(s);

    float nll;
    if (t < 20000) {
        const float* wr0 = w0 + (size_t)t * 1024;
        float d = 0.f;
        for (int k = lane * 4; k < 1024; k += 256) {
            ushort4 a = *(const ushort4*)(Hrow + k);
            float4  b = *(const float4*)(wr0 + k);
            d += bf2f(a.x) * b.x + bf2f(a.y) * b.y + bf2f(a.z) * b.z + bf2f(a.w) * b.w;
        }
        #pragma unroll
        for (int off = 32; off; off >>= 1) d += __shfl_xor(d, off);
        nll = -(d + b0[t] - logSh);
    } else {
        const int i  = (t - 20000) / 10000 + 1;        // 1..3
        const int ci = 3 - i;                           // head_lp[:, -i] quirk
        const float* cwr = cw + (size_t)ci * 1024;
        float d = 0.f;
        for (int k = lane * 4; k < 1024; k += 256) {
            ushort4 a = *(const ushort4*)(Hrow + k);
            float4  b = *(const float4*)(cwr + k);
            d += bf2f(a.x) * b.x + bf2f(a.y) * b.y + bf2f(a.z) * b.z + bf2f(a.w) * b.w;
        }
        #pragma unroll
        for (int off = 32; off; off >>= 1) d += __shfl_xor(d, off);
        const float logit_c = d + cbv[ci];

        const int dl   = 1024 >> (2 * i);               // 256, 64, 16
        const int hoff = (i == 1) ? 1024 : (i == 2) ? 1280 : 1344;
        const float* wi = (i == 1) ? w1 : (i == 2) ? w2 : w3;
        const float* bi = (i == 1) ? b1 : (i == 2) ? b2 : b3;
        const float* pT = (i == 1) ? pT1 : (i == 2) ? pT2 : pT3;
        const int nbi  = (i == 1) ? NBT1 : NBT;
        const int tt = t - (20000 + (i - 1) * 10000);

        float dt = 0.f;
        const ushort* Hi = Hrow + hoff;
        for (int k = lane; k < dl; k += 64) dt += bf2f(Hi[k]) * wi[(size_t)tt * dl + k];
        #pragma unroll
        for (int off = 32; off; off >>= 1) dt += __shfl_xor(dt, off);

        float st = 0.f;
        for (int c = lane; c < nbi; c += 64) st += pT[(size_t)row * nbi + c];
        #pragma unroll
        for (int off = 32; off; off >>= 1) st += __shfl_xor(st, off);

        nll = -((logit_c - logSh) + (dt + bi[tt] - logf(st)));
    }
    if (lane == 0) out[row] = nll;
}

// ---------------------------------------------------------------------------
extern "C" void kernel_launch(void* const* d_in, const int* in_sizes, int n_in,
                              void* d_out, int out_size, void* d_ws, size_t ws_size,
                              hipStream_t stream) {
    const float* hidden = (const float*)d_in[0];
    const int*   target = (const int*)  d_in[1];
    const float* proj0  = (const float*)d_in[2];
    const float* w0     = (const float*)d_in[3];
    const float* b0     = (const float*)d_in[4];
    const float* proj1  = (const float*)d_in[5];
    const float* w1     = (const float*)d_in[6];
    const float* b1     = (const float*)d_in[7];
    const float* proj2  = (const float*)d_in[8];
    const float* w2     = (const float*)d_in[9];
    const float* b2     = (const float*)d_in[10];
    const float* proj3  = (const float*)d_in[11];
    const float* w3     = (const float*)d_in[12];
    const float* b3     = (const float*)d_in[13];
    const float* cw     = (const float*)d_in[14];
    const float* cbv    = (const float*)d_in[15];

    ushort* hb  = (ushort*)d_ws;                         // [4096][1024]
    ushort* pbT = hb  + (size_t)NROW * DPROJ;            // [1408][1024]
    ushort* Hb  = pbT + (size_t)LDHB * DPROJ;            // [4096][1408]
    ushort* WH  = Hb  + (size_t)NROW * LDHB;             // [20224][1024]
    ushort* WT1 = WH  + (size_t)HEAD_VP * 1024;          // [10240][256]
    ushort* WT2 = WT1 + (size_t)TAIL1_P * 256;           // [10112][64]
    ushort* WT3 = WT2 + (size_t)TAIL_VP * 64;            // [10112][32]
    float*  pH  = (float*)(WT3 + (size_t)TAIL_VP * 32);  // [4096][79]
    float*  pT1 = pH  + (size_t)NROW * NBH;              // [4096][40]
    float*  pT2 = pT1 + (size_t)NROW * NBT1;             // [4096][79]
    float*  pT3 = pT2 + (size_t)NROW * NBT;              // [4096][79]

    dim3 blk(256);
    cast_hidden_k<<<dim3(NROW * DPROJ / 1024), blk, 0, stream>>>(hidden, hb);
    cast_transpose_proj<<<dim3(16, 22), blk, 0, stream>>>(proj0, proj1, proj2, proj3, pbT);
    cast_head_w<<<dim3(HEAD_VP), blk, 0, stream>>>(w0, cw, WH);
    cast_tail_w<256><<<dim3(TAIL1_P), blk, 0, stream>>>(w1, WT1, TAIL_V, 256, TAIL1_P);
    cast_tail_w<64><<<dim3((TAIL_VP * 64 + 255) / 256), blk, 0, stream>>>(w2, WT2, TAIL_V, 64, TAIL_VP);
    cast_tail_w<32><<<dim3((TAIL_VP * 32 + 255) / 256), blk, 0, stream>>>(w3, WT3, TAIL_V, 16, TAIL_VP);

    proj_gemm_mfma<<<dim3(32, 11), blk, 0, stream>>>(hb, pbT, Hb);

    // head: 16 x 79 = 1264 blocks (%8==0), 128 KB dynamic LDS
    gemm_sumexp_t4<1024><<<dim3(16 * NBH), dim3(512), 131072, stream>>>(
        Hb, LDHB, WH, b0, cbv, 20000, HEAD_V, pH, NBH, 16);
    // tail1: 16 x 40 = 640 blocks
    gemm_sumexp_t4<256><<<dim3(16 * NBT1), dim3(512), 131072, stream>>>(
        Hb + 1024, LDHB, WT1, b1, b1, TAIL_V, TAIL_V, pT1, NBT1, 16);
    // tails 2,3 on the 128-tile kernel
    gemm_sumexp_bf<64><<<dim3(32, NBT), blk, 0, stream>>>(
        Hb + 1280, WT2, b2, TAIL_V, pT2, NBT);
    gemm_sumexp_bf<32><<<dim3(32, NBT), blk, 0, stream>>>(
        Hb + 1344, WT3, b3, TAIL_V, pT3, NBT);

    pals_finalize<<<dim3(NROW / 4), blk, 0, stream>>>(
        Hb, target, w0, b0, w1, b1, w2, b2, w3, b3, cw, cbv,
        pH, pT1, pT2, pT3, (float*)d_out);
}

// Round 7
// 561.355 us; speedup vs baseline: 1.0685x; 1.0393x over previous
//
#include <hip/hip_runtime.h>
#include <hip/hip_bf16.h>
#include <math.h>

// Problem sizes (fixed)
#define NROW    4096
#define DPROJ   1024
#define LDHB    1408         // Hb row stride (bf16 elems)
#define LDA8    1280         // A8 row stride (bytes): 1024 head + 256 tail1
#define HEAD_V  20003
#define TAIL_V  10000
#define HEAD_VP 20224        // 79*256
#define TAIL1_P 10240        // 40*256
#define TAIL_VP 10112        // 79*128 (tails 2,3 on 128-tile bf16 kernel)
#define NBH     79
#define NBT1    40
#define NBT     79

typedef short short8 __attribute__((ext_vector_type(8)));
typedef float f32x4  __attribute__((ext_vector_type(4)));
typedef long  i64x2  __attribute__((ext_vector_type(2)));

__device__ __forceinline__ ushort f2bf(float f) {           // RNE f32 -> bf16
    unsigned u = __builtin_bit_cast(unsigned, f);
    return (ushort)((u + 0x7FFFu + ((u >> 16) & 1u)) >> 16);
}
__device__ __forceinline__ float bf2f(ushort u) {
    unsigned x = (unsigned)u << 16;
    return __builtin_bit_cast(float, x);
}
// within-128 K permutation: stored q -> logical k (lane-contig 16B per 2 k-steps)
__device__ __forceinline__ int kperm(int q) {
    int q7 = q & 127;
    return (q & ~127) + ((q7 >> 3) & 3) * 32 + ((q7 >> 5) << 3) + (q7 & 7);
}

#define GLOAD16(gp, lp) __builtin_amdgcn_global_load_lds(                     \
    (const __attribute__((address_space(1))) void*)(gp),                      \
    (__attribute__((address_space(3))) void*)(lp), 16, 0, 0)

// ---------------------------------------------------------------------------
// cast hidden f32 -> bf16
// ---------------------------------------------------------------------------
__global__ void cast_hidden_k(const float* __restrict__ h, ushort* __restrict__ hb) {
    int i = (blockIdx.x * 256 + threadIdx.x) * 4;
    float4 v = *(const float4*)(h + i);
    ushort4 o = {f2bf(v.x), f2bf(v.y), f2bf(v.z), f2bf(v.w)};
    *(ushort4*)(hb + i) = o;
}

// ---------------------------------------------------------------------------
// transpose-cast proj concat -> pbT [1408][1024] bf16
// ---------------------------------------------------------------------------
__global__ void cast_transpose_proj(const float* __restrict__ p0, const float* __restrict__ p1,
                                    const float* __restrict__ p2, const float* __restrict__ p3,
                                    ushort* __restrict__ pbT) {
    __shared__ float tile[64][65];
    const int t  = threadIdx.x;
    const int kb = blockIdx.x * 64;
    const int cb = blockIdx.y * 64;
    for (int p = 0; p < 4; ++p) {
        int kl = p * 16 + (t >> 4);
        int c4 = (t & 15) * 4;
        int k  = kb + kl;
        for (int j = 0; j < 4; ++j) {
            int c = cb + c4 + j;
            float v = 0.f;
            if      (c < 1024) v = p0[(size_t)k * 1024 + c];
            else if (c < 1280) v = p1[(size_t)k * 256  + (c - 1024)];
            else if (c < 1344) v = p2[(size_t)k * 64   + (c - 1280)];
            else if (c < 1360) v = p3[(size_t)k * 16   + (c - 1344)];
            tile[kl][c4 + j] = v;
        }
    }
    __syncthreads();
    for (int p = 0; p < 4; ++p) {
        int cl = p * 16 + (t >> 4);
        int k4 = (t & 15) * 4;
        ushort4 o = {f2bf(tile[k4 + 0][cl]), f2bf(tile[k4 + 1][cl]),
                     f2bf(tile[k4 + 2][cl]), f2bf(tile[k4 + 3][cl])};
        *(ushort4*)(pbT + (size_t)(cb + cl) * 1024 + kb + k4) = o;
    }
}

// ---------------------------------------------------------------------------
// fp8 casts (e4m3 OCP, K-permuted layout)
// ---------------------------------------------------------------------------
__global__ void cast_head_w8(const float* __restrict__ w0, const float* __restrict__ cw,
                             unsigned char* __restrict__ dst) {
    int row = blockIdx.x;                       // 20224
    int q   = threadIdx.x * 4;
    int k   = kperm(q);
    float4 v = {0.f, 0.f, 0.f, 0.f};
    if (row < 20000)      v = *(const float4*)(w0 + (size_t)row * 1024 + k);
    else if (row < 20003) v = *(const float4*)(cw + (size_t)(row - 20000) * 1024 + k);
    int p = __builtin_amdgcn_cvt_pk_fp8_f32(v.x, v.y, 0, false);
    p     = __builtin_amdgcn_cvt_pk_fp8_f32(v.z, v.w, p, true);
    *(int*)(dst + (size_t)row * 1024 + q) = p;
}

__global__ void cast_t1_w8(const float* __restrict__ w1, unsigned char* __restrict__ dst) {
    int row = blockIdx.x;                       // 10240
    if (threadIdx.x >= 64) return;
    int q = threadIdx.x * 4;
    int k = kperm(q);
    float4 v = {0.f, 0.f, 0.f, 0.f};
    if (row < 10000) v = *(const float4*)(w1 + (size_t)row * 256 + k);
    int p = __builtin_amdgcn_cvt_pk_fp8_f32(v.x, v.y, 0, false);
    p     = __builtin_amdgcn_cvt_pk_fp8_f32(v.z, v.w, p, true);
    *(int*)(dst + (size_t)row * 256 + q) = p;
}

__global__ void cast_A8(const ushort* __restrict__ Hb, unsigned char* __restrict__ dst) {
    int row = blockIdx.x;                       // 4096
    for (int i = threadIdx.x; i < LDA8 / 4; i += 256) {
        int q = i * 4;
        int k = kperm(q);
        const ushort* s = Hb + (size_t)row * LDHB + k;
        int p = __builtin_amdgcn_cvt_pk_fp8_f32(bf2f(s[0]), bf2f(s[1]), 0, false);
        p     = __builtin_amdgcn_cvt_pk_fp8_f32(bf2f(s[2]), bf2f(s[3]), p, true);
        *(int*)(dst + (size_t)row * LDA8 + q) = p;
    }
}

// ---------------------------------------------------------------------------
// cast tail weight (bf16, tails 2/3): src [rows_real][kin] -> dst [rows_pad][KOUT]
// ---------------------------------------------------------------------------
template<int KOUT>
__global__ void cast_tail_w(const float* __restrict__ src, ushort* __restrict__ dst,
                            int rows_real, int kin, int rows_pad) {
    int idx = blockIdx.x * 256 + threadIdx.x;
    const int n = rows_pad * KOUT;
    if (idx >= n) return;
    int r = idx / KOUT, k = idx - r * KOUT;
    float v = (r < rows_real && k < kin) ? src[(size_t)r * kin + k] : 0.f;
    dst[idx] = f2bf(v);
}

// ---------------------------------------------------------------------------
// Proj GEMM: Hb[4096][1408] = hb @ pbT^T  (m97 128x128, bf16, unchanged)
// ---------------------------------------------------------------------------
__global__ __launch_bounds__(256) void proj_gemm_mfma(const ushort* __restrict__ A,
                                                      const ushort* __restrict__ B,
                                                      ushort* __restrict__ C) {
    __shared__ ushort As[128 * 32];
    __shared__ ushort Bs[128 * 32];
    const int t  = threadIdx.x;
    const int wv = t >> 6, l = t & 63, lr = l & 15, lh = l >> 4;
    const int wr = wv >> 1, wc = wv & 1;
    const int rb = blockIdx.x * 128, cb = blockIdx.y * 128;
    f32x4 acc[4][4] = {};
    for (int k0 = 0; k0 < DPROJ; k0 += 32) {
        __syncthreads();
        #pragma unroll
        for (int is = 0; is < 2; ++is) {
            int rr = (t >> 2) + is * 64;
            GLOAD16(A + (size_t)(rb + rr) * DPROJ + k0 + (t & 3) * 8,
                    (char*)As + wv * 1024 + is * 4096);
            GLOAD16(B + (size_t)(cb + rr) * DPROJ + k0 + (t & 3) * 8,
                    (char*)Bs + wv * 1024 + is * 4096);
        }
        __syncthreads();
        short8 af[4], bf[4];
        #pragma unroll
        for (int m = 0; m < 4; ++m)
            af[m] = *(const short8*)(As + (wr * 64 + m * 16 + lr) * 32 + lh * 8);
        #pragma unroll
        for (int n = 0; n < 4; ++n)
            bf[n] = *(const short8*)(Bs + (wc * 64 + n * 16 + lr) * 32 + lh * 8);
        #pragma unroll
        for (int m = 0; m < 4; ++m)
            #pragma unroll
            for (int n = 0; n < 4; ++n)
                acc[m][n] = __builtin_amdgcn_mfma_f32_16x16x32_bf16(af[m], bf[n], acc[m][n], 0, 0, 0);
    }
    #pragma unroll
    for (int m = 0; m < 4; ++m)
        #pragma unroll
        for (int n = 0; n < 4; ++n)
            #pragma unroll
            for (int r = 0; r < 4; ++r) {
                int rl = wr * 64 + m * 16 + lh * 4 + r;
                int cl = wc * 64 + n * 16 + lr;
                C[(size_t)(rb + rl) * LDHB + cb + cl] = f2bf(acc[m][n][r]);
            }
}

// ---------------------------------------------------------------------------
// FP8 256x256 GEMM + sum-exp. BK=128 bytes, counted-vmcnt 4-phase pipeline.
// LDS 128 KB: A[2][256][128B] | B[2][256][128B], swizzle byte^=(row&7)<<4.
// Per K-tile: 8 gloads (one half per phase), vmcnt(4) at boundary.
// ---------------------------------------------------------------------------
template<int K>
__global__ __launch_bounds__(512, 2) void gemm_sumexp_f8(
        const unsigned char* __restrict__ A, int lda,
        const unsigned char* __restrict__ B,
        const float* __restrict__ bias, const float* __restrict__ biasx,
        int splitB, int vocab,
        float* __restrict__ partial, int nCB, int gridM) {
    extern __shared__ char lds[];
    const int t  = threadIdx.x;
    const int wv = t >> 6, l = t & 63, lr = l & 15, lh = l >> 4;
    const int wr = wv >> 2, wc = wv & 3;             // 2M x 4N waves
    const int cpx = gridDim.x >> 3;                  // XCD swizzle (grid%8==0)
    const int bid = blockIdx.x;
    const int swzb = (bid & 7) * cpx + (bid >> 3);
    const int bm = swzb % gridM, bn = swzb / gridM;
    const int rb = bm * 256, cb = bn * 256;
    constexpr int NT = K / 128;

    const int srow  = t >> 3;                        // 0..63
    const int scolb = (t & 7) * 16;                  // byte col in row
    const int csw   = scolb ^ ((srow & 7) << 4);     // pre-inverse-swizzled src

    auto stageA = [&](int h, int kt) {
        if (kt >= NT) return;
        const int buf = kt & 1, k0 = kt * 128;
        #pragma unroll
        for (int j = 0; j < 2; ++j) {
            int row = h * 128 + j * 64 + srow;
            GLOAD16(A + (size_t)(rb + row) * lda + k0 + csw,
                    lds + buf * 32768 + (h * 128 + j * 64 + wv * 8) * 128);
        }
    };
    auto stageB = [&](int h, int kt) {
        if (kt >= NT) return;
        const int buf = kt & 1, k0 = kt * 128;
        #pragma unroll
        for (int j = 0; j < 2; ++j) {
            int row = h * 128 + j * 64 + srow;
            GLOAD16(B + (size_t)(cb + row) * K + k0 + csw,
                    lds + 65536 + buf * 32768 + (h * 128 + j * 64 + wv * 8) * 128);
        }
    };

    i64x2 af[8], bf0[4], bf1[4];
    f32x4 acc[8][4] = {};
    auto rdA = [&](int buf, int mh) {
        #pragma unroll
        for (int m = 0; m < 4; ++m)
            #pragma unroll
            for (int s = 0; s < 2; ++s) {
                int row = wr * 128 + (mh * 4 + m) * 16 + lr;
                int eb  = (lh * 32 + s * 16) ^ ((row & 7) << 4);
                af[m * 2 + s] = *(const i64x2*)(lds + buf * 32768 + row * 128 + eb);
            }
    };
    auto rdB = [&](int buf, int nh, i64x2* bf) {
        #pragma unroll
        for (int n = 0; n < 2; ++n)
            #pragma unroll
            for (int s = 0; s < 2; ++s) {
                int row = wc * 64 + (nh * 2 + n) * 16 + lr;
                int eb  = (lh * 32 + s * 16) ^ ((row & 7) << 4);
                bf[n * 2 + s] = *(const i64x2*)(lds + 65536 + buf * 32768 + row * 128 + eb);
            }
    };
    auto mf32 = [&](int mh, int nh, i64x2* bf) {     // 32 MFMA quadrant (K=128)
        __builtin_amdgcn_s_setprio(1);
        #pragma unroll
        for (int m = 0; m < 4; ++m)
            #pragma unroll
            for (int n = 0; n < 2; ++n) {
                f32x4 c = acc[mh * 4 + m][nh * 2 + n];
                #pragma unroll
                for (int s = 0; s < 2; ++s) {
                    c = __builtin_amdgcn_mfma_f32_16x16x32_fp8_fp8(af[m * 2 + s].x, bf[n * 2 + s].x, c, 0, 0, 0);
                    c = __builtin_amdgcn_mfma_f32_16x16x32_fp8_fp8(af[m * 2 + s].y, bf[n * 2 + s].y, c, 0, 0, 0);
                }
                acc[mh * 4 + m][nh * 2 + n] = c;
            }
        __builtin_amdgcn_s_setprio(0);
    };

    // prologue: tile0 full (8 loads) + tile1 h0 halves (4 loads); vmcnt(4) -> tile0 landed
    stageB(0, 0); stageA(0, 0); stageB(1, 0); stageA(1, 0);
    stageB(0, 1); stageA(0, 1);
    if (NT > 1) asm volatile("s_waitcnt vmcnt(4)" ::: "memory");
    else        asm volatile("s_waitcnt vmcnt(0)" ::: "memory");
    __builtin_amdgcn_s_barrier();

    for (int kt = 0; kt < NT; ++kt) {
        const int buf = kt & 1;
        // ph0: A[m0-3] + B[n0-1] reads; stage Bh1(kt+1)
        rdA(buf, 0);
        rdB(buf, 0, bf0);
        stageB(1, kt + 1);
        __builtin_amdgcn_s_barrier();
        asm volatile("s_waitcnt lgkmcnt(0)" ::: "memory");
        __builtin_amdgcn_sched_barrier(0);
        mf32(0, 0, bf0);
        __builtin_amdgcn_s_barrier();
        // ph1: B[n2-3] reads; stage Ah1(kt+1)
        rdB(buf, 1, bf1);
        stageA(1, kt + 1);
        __builtin_amdgcn_s_barrier();
        asm volatile("s_waitcnt lgkmcnt(0)" ::: "memory");
        __builtin_amdgcn_sched_barrier(0);
        mf32(0, 1, bf1);
        __builtin_amdgcn_s_barrier();
        // ph2: A[m4-7] reads; stage Bh0(kt+2)
        rdA(buf, 1);
        stageB(0, kt + 2);
        __builtin_amdgcn_s_barrier();
        asm volatile("s_waitcnt lgkmcnt(0)" ::: "memory");
        __builtin_amdgcn_sched_barrier(0);
        mf32(1, 1, bf1);
        __builtin_amdgcn_s_barrier();
        // ph3: no ds reads; stage Ah0(kt+2); counted boundary wait
        stageA(0, kt + 2);
        mf32(1, 0, bf0);
        if (kt + 2 < NT)      asm volatile("s_waitcnt vmcnt(4)" ::: "memory");
        else if (kt + 1 < NT) asm volatile("s_waitcnt vmcnt(0)" ::: "memory");
        __builtin_amdgcn_s_barrier();
    }

    // epilogue: exp(logit+bias), per-row sums; staging LDS dead -> red[4][256]
    float* red = (float*)lds;
    #pragma unroll
    for (int m = 0; m < 8; ++m)
        #pragma unroll
        for (int q = 0; q < 4; ++q) {
            float s = 0.f;
            #pragma unroll
            for (int n = 0; n < 4; ++n) {
                int col = cb + wc * 64 + n * 16 + lr;
                if (col < vocab) {
                    float bv = (col < splitB) ? bias[col] : biasx[col - splitB];
                    s += expf(acc[m][n][q] + bv);
                }
            }
            #pragma unroll
            for (int off = 1; off < 16; off <<= 1) s += __shfl_xor(s, off);
            if (lr == 0) red[wc * 256 + wr * 128 + m * 16 + lh * 4 + q] = s;
        }
    __syncthreads();
    if (t < 256)
        partial[(size_t)(rb + t) * nCB + bn] =
            red[t] + red[256 + t] + red[512 + t] + red[768 + t];
}

// ---------------------------------------------------------------------------
// 128x128 m97-style bf16 GEMM + sum-exp (tails 2,3)
// ---------------------------------------------------------------------------
template<int K>
__global__ __launch_bounds__(256) void gemm_sumexp_bf(
        const ushort* __restrict__ A,
        const ushort* __restrict__ B,
        const float* __restrict__ bias,
        int vocab, float* __restrict__ partial, int nCB) {
    __shared__ ushort As[128 * 32];
    __shared__ ushort Bs[128 * 32];
    __shared__ float  red[2][128];
    const int t  = threadIdx.x;
    const int wv = t >> 6, l = t & 63, lr = l & 15, lh = l >> 4;
    const int wr = wv >> 1, wc = wv & 1;
    const int rb = blockIdx.x * 128, cb = blockIdx.y * 128;
    f32x4 acc[4][4] = {};
    for (int k0 = 0; k0 < K; k0 += 32) {
        __syncthreads();
        #pragma unroll
        for (int is = 0; is < 2; ++is) {
            int rr = (t >> 2) + is * 64;
            GLOAD16(A + (size_t)(rb + rr) * LDHB + k0 + (t & 3) * 8,
                    (char*)As + wv * 1024 + is * 4096);
            GLOAD16(B + (size_t)(cb + rr) * K + k0 + (t & 3) * 8,
                    (char*)Bs + wv * 1024 + is * 4096);
        }
        __syncthreads();
        short8 af[4], bf[4];
        #pragma unroll
        for (int m = 0; m < 4; ++m)
            af[m] = *(const short8*)(As + (wr * 64 + m * 16 + lr) * 32 + lh * 8);
        #pragma unroll
        for (int n = 0; n < 4; ++n)
            bf[n] = *(const short8*)(Bs + (wc * 64 + n * 16 + lr) * 32 + lh * 8);
        #pragma unroll
        for (int m = 0; m < 4; ++m)
            #pragma unroll
            for (int n = 0; n < 4; ++n)
                acc[m][n] = __builtin_amdgcn_mfma_f32_16x16x32_bf16(af[m], bf[n], acc[m][n], 0, 0, 0);
    }
    float rs[4][4];
    #pragma unroll
    for (int m = 0; m < 4; ++m)
        #pragma unroll
        for (int r = 0; r < 4; ++r) {
            float s = 0.f;
            #pragma unroll
            for (int n = 0; n < 4; ++n) {
                int col = cb + wc * 64 + n * 16 + lr;
                if (col < vocab) s += expf(acc[m][n][r] + bias[col]);
            }
            rs[m][r] = s;
        }
    #pragma unroll
    for (int m = 0; m < 4; ++m)
        #pragma unroll
        for (int r = 0; r < 4; ++r) {
            #pragma unroll
            for (int off = 1; off < 16; off <<= 1)
                rs[m][r] += __shfl_xor(rs[m][r], off);
            if (lr == 0) red[wc][wr * 64 + m * 16 + lh * 4 + r] = rs[m][r];
        }
    __syncthreads();
    if (t < 128)
        partial[(size_t)(rb + t) * nCB + blockIdx.y] = red[0][t] + red[1][t];
}

// ---------------------------------------------------------------------------
// Finalize: one wave per row — gather target/cluster logits (fp32), assemble NLL.
// ---------------------------------------------------------------------------
__global__ void pals_finalize(const ushort* __restrict__ Hb,
                              const int* __restrict__ target,
                              const float* __restrict__ w0, const float* __restrict__ b0,
                              const float* __restrict__ w1, const float* __restrict__ b1,
                              const float* __restrict__ w2, const float* __restrict__ b2,
                              const float* __restrict__ w3, const float* __restrict__ b3,
                              const float* __restrict__ cw, const float* __restrict__ cbv,
                              const float* __restrict__ pH,
                              const float* __restrict__ pT1,
                              const float* __restrict__ pT2,
                              const float* __restrict__ pT3,
                              float* __restrict__ out) {
    const int wave = threadIdx.x >> 6;
    const int lane = threadIdx.x & 63;
    const int row  = blockIdx.x * 4 + wave;
    if (row >= NROW) return;
    const int t = target[row];
    const ushort* Hrow = Hb + (size_t)row * LDHB;

    float s = 0.f;
    for (int c = lane; c < NBH; c += 64) s += pH[(size_t)row * NBH + c];
    #pragma unroll
    for (int off = 32; off; off >>= 1) s += __shfl_xor(s, off);
    const float logSh = logf(s);

    float nll;
    if (t < 20000) {
        const float* wr0 = w0 + (size_t)t * 1024;
        float d = 0.f;
        for (int k = lane * 4; k < 1024; k += 256) {
            ushort4 a = *(const ushort4*)(Hrow + k);
            float4  b = *(const float4*)(wr0 + k);
            d += bf2f(a.x) * b.x + bf2f(a.y) * b.y + bf2f(a.z) * b.z + bf2f(a.w) * b.w;
        }
        #pragma unroll
        for (int off = 32; off; off >>= 1) d += __shfl_xor(d, off);
        nll = -(d + b0[t] - logSh);
    } else {
        const int i  = (t - 20000) / 10000 + 1;        // 1..3
        const int ci = 3 - i;                           // head_lp[:, -i] quirk
        const float* cwr = cw + (size_t)ci * 1024;
        float d = 0.f;
        for (int k = lane * 4; k < 1024; k += 256) {
            ushort4 a = *(const ushort4*)(Hrow + k);
            float4  b = *(const float4*)(cwr + k);
            d += bf2f(a.x) * b.x + bf2f(a.y) * b.y + bf2f(a.z) * b.z + bf2f(a.w) * b.w;
        }
        #pragma unroll
        for (int off = 32; off; off >>= 1) d += __shfl_xor(d, off);
        const float logit_c = d + cbv[ci];

        const int dl   = 1024 >> (2 * i);               // 256, 64, 16
        const int hoff = (i == 1) ? 1024 : (i == 2) ? 1280 : 1344;
        const float* wi = (i == 1) ? w1 : (i == 2) ? w2 : w3;
        const float* bi = (i == 1) ? b1 : (i == 2) ? b2 : b3;
        const float* pT = (i == 1) ? pT1 : (i == 2) ? pT2 : pT3;
        const int nbi  = (i == 1) ? NBT1 : NBT;
        const int tt = t - (20000 + (i - 1) * 10000);

        float dt = 0.f;
        const ushort* Hi = Hrow + hoff;
        for (int k = lane; k < dl; k += 64) dt += bf2f(Hi[k]) * wi[(size_t)tt * dl + k];
        #pragma unroll
        for (int off = 32; off; off >>= 1) dt += __shfl_xor(dt, off);

        float st = 0.f;
        for (int c = lane; c < nbi; c += 64) st += pT[(size_t)row * nbi + c];
        #pragma unroll
        for (int off = 32; off; off >>= 1) st += __shfl_xor(st, off);

        nll = -((logit_c - logSh) + (dt + bi[tt] - logf(st)));
    }
    if (lane == 0) out[row] = nll;
}

// ---------------------------------------------------------------------------
extern "C" void kernel_launch(void* const* d_in, const int* in_sizes, int n_in,
                              void* d_out, int out_size, void* d_ws, size_t ws_size,
                              hipStream_t stream) {
    const float* hidden = (const float*)d_in[0];
    const int*   target = (const int*)  d_in[1];
    const float* proj0  = (const float*)d_in[2];
    const float* w0     = (const float*)d_in[3];
    const float* b0     = (const float*)d_in[4];
    const float* proj1  = (const float*)d_in[5];
    const float* w1     = (const float*)d_in[6];
    const float* b1     = (const float*)d_in[7];
    const float* proj2  = (const float*)d_in[8];
    const float* w2     = (const float*)d_in[9];
    const float* b2     = (const float*)d_in[10];
    const float* proj3  = (const float*)d_in[11];
    const float* w3     = (const float*)d_in[12];
    const float* b3     = (const float*)d_in[13];
    const float* cw     = (const float*)d_in[14];
    const float* cbv    = (const float*)d_in[15];

    ushort* hb  = (ushort*)d_ws;                         // [4096][1024]
    ushort* pbT = hb  + (size_t)NROW * DPROJ;            // [1408][1024]
    ushort* Hb  = pbT + (size_t)LDHB * DPROJ;            // [4096][1408]
    ushort* WT2 = Hb  + (size_t)NROW * LDHB;             // [10112][64]
    ushort* WT3 = WT2 + (size_t)TAIL_VP * 64;            // [10112][32]
    unsigned char* WH8  = (unsigned char*)(WT3 + (size_t)TAIL_VP * 32);  // [20224][1024]
    unsigned char* WT18 = WH8  + (size_t)HEAD_VP * 1024;                 // [10240][256]
    unsigned char* A8   = WT18 + (size_t)TAIL1_P * 256;                  // [4096][1280]
    float*  pH  = (float*)(A8 + (size_t)NROW * LDA8);    // [4096][79]
    float*  pT1 = pH  + (size_t)NROW * NBH;              // [4096][40]
    float*  pT2 = pT1 + (size_t)NROW * NBT1;             // [4096][79]
    float*  pT3 = pT2 + (size_t)NROW * NBT;              // [4096][79]

    dim3 blk(256);
    cast_hidden_k<<<dim3(NROW * DPROJ / 1024), blk, 0, stream>>>(hidden, hb);
    cast_transpose_proj<<<dim3(16, 22), blk, 0, stream>>>(proj0, proj1, proj2, proj3, pbT);
    cast_head_w8<<<dim3(HEAD_VP), blk, 0, stream>>>(w0, cw, WH8);
    cast_t1_w8<<<dim3(TAIL1_P), blk, 0, stream>>>(w1, WT18);
    cast_tail_w<64><<<dim3((TAIL_VP * 64 + 255) / 256), blk, 0, stream>>>(w2, WT2, TAIL_V, 64, TAIL_VP);
    cast_tail_w<32><<<dim3((TAIL_VP * 32 + 255) / 256), blk, 0, stream>>>(w3, WT3, TAIL_V, 16, TAIL_VP);

    proj_gemm_mfma<<<dim3(32, 11), blk, 0, stream>>>(hb, pbT, Hb);
    cast_A8<<<dim3(NROW), blk, 0, stream>>>(Hb, A8);

    // head: 16 x 79 = 1264 blocks (%8==0), 128 KB dynamic LDS, fp8
    gemm_sumexp_f8<1024><<<dim3(16 * NBH), dim3(512), 131072, stream>>>(
        A8, LDA8, WH8, b0, cbv, 20000, HEAD_V, pH, NBH, 16);
    // tail1: 16 x 40 = 640 blocks, fp8 (A base offset 1024 bytes into A8 rows)
    gemm_sumexp_f8<256><<<dim3(16 * NBT1), dim3(512), 131072, stream>>>(
        A8 + 1024, LDA8, WT18, b1, b1, TAIL_V, TAIL_V, pT1, NBT1, 16);
    // tails 2,3 on the 128-tile bf16 kernel
    gemm_sumexp_bf<64><<<dim3(32, NBT), blk, 0, stream>>>(
        Hb + 1280, WT2, b2, TAIL_V, pT2, NBT);
    gemm_sumexp_bf<32><<<dim3(32, NBT), blk, 0, stream>>>(
        Hb + 1344, WT3, b3, TAIL_V, pT3, NBT);

    pals_finalize<<<dim3(NROW / 4), blk, 0, stream>>>(
        Hb, target, w0, b0, w1, b1, w2, b2, w3, b3, cw, cbv,
        pH, pT1, pT2, pT3, (float*)d_out);
}

// Round 8
// 392.649 us; speedup vs baseline: 1.5276x; 1.4297x over previous
//
#include <hip/hip_runtime.h>
#include <hip/hip_bf16.h>
#include <math.h>

// Problem sizes (fixed)
#define NROW    4096
#define DPROJ   1024
#define LDHB    1408         // Hb row stride (bf16 elems)
#define LDA8    1280         // A8 row stride (bytes): 1024 head + 256 tail1
#define HEAD_V  20003
#define TAIL_V  10000
#define HEAD_VP 20224        // 158*128
#define TAIL1_P 10240        // 80*128
#define TAIL_VP 10112        // 79*128 (tails 2,3 on 128-tile bf16 kernel)
#define NBH     158          // head col-blocks (128 wide)
#define NBT1    80           // tail1 col-blocks (128 wide)
#define NBT     79           // tail2/3 col-blocks (128 wide)

typedef short short8 __attribute__((ext_vector_type(8)));
typedef float f32x4  __attribute__((ext_vector_type(4)));
typedef long  i64x2  __attribute__((ext_vector_type(2)));

__device__ __forceinline__ ushort f2bf(float f) {           // RNE f32 -> bf16
    unsigned u = __builtin_bit_cast(unsigned, f);
    return (ushort)((u + 0x7FFFu + ((u >> 16) & 1u)) >> 16);
}
__device__ __forceinline__ float bf2f(ushort u) {
    unsigned x = (unsigned)u << 16;
    return __builtin_bit_cast(float, x);
}
// within-128 K permutation: stored q -> logical k (lane-contig 16B per 2 k-steps)
__device__ __forceinline__ int kperm(int q) {
    int q7 = q & 127;
    return (q & ~127) + ((q7 >> 3) & 3) * 32 + ((q7 >> 5) << 3) + (q7 & 7);
}

#define GLOAD16(gp, lp) __builtin_amdgcn_global_load_lds(                     \
    (const __attribute__((address_space(1))) void*)(gp),                      \
    (__attribute__((address_space(3))) void*)(lp), 16, 0, 0)

// ---------------------------------------------------------------------------
// cast hidden f32 -> bf16
// ---------------------------------------------------------------------------
__global__ void cast_hidden_k(const float* __restrict__ h, ushort* __restrict__ hb) {
    int i = (blockIdx.x * 256 + threadIdx.x) * 4;
    float4 v = *(const float4*)(h + i);
    ushort4 o = {f2bf(v.x), f2bf(v.y), f2bf(v.z), f2bf(v.w)};
    *(ushort4*)(hb + i) = o;
}

// ---------------------------------------------------------------------------
// transpose-cast proj concat -> pbT [1408][1024] bf16
// ---------------------------------------------------------------------------
__global__ void cast_transpose_proj(const float* __restrict__ p0, const float* __restrict__ p1,
                                    const float* __restrict__ p2, const float* __restrict__ p3,
                                    ushort* __restrict__ pbT) {
    __shared__ float tile[64][65];
    const int t  = threadIdx.x;
    const int kb = blockIdx.x * 64;
    const int cb = blockIdx.y * 64;
    for (int p = 0; p < 4; ++p) {
        int kl = p * 16 + (t >> 4);
        int c4 = (t & 15) * 4;
        int k  = kb + kl;
        for (int j = 0; j < 4; ++j) {
            int c = cb + c4 + j;
            float v = 0.f;
            if      (c < 1024) v = p0[(size_t)k * 1024 + c];
            else if (c < 1280) v = p1[(size_t)k * 256  + (c - 1024)];
            else if (c < 1344) v = p2[(size_t)k * 64   + (c - 1280)];
            else if (c < 1360) v = p3[(size_t)k * 16   + (c - 1344)];
            tile[kl][c4 + j] = v;
        }
    }
    __syncthreads();
    for (int p = 0; p < 4; ++p) {
        int cl = p * 16 + (t >> 4);
        int k4 = (t & 15) * 4;
        ushort4 o = {f2bf(tile[k4 + 0][cl]), f2bf(tile[k4 + 1][cl]),
                     f2bf(tile[k4 + 2][cl]), f2bf(tile[k4 + 3][cl])};
        *(ushort4*)(pbT + (size_t)(cb + cl) * 1024 + kb + k4) = o;
    }
}

// ---------------------------------------------------------------------------
// fp8 casts (e4m3 OCP, K-permuted layout)
// ---------------------------------------------------------------------------
__global__ void cast_head_w8(const float* __restrict__ w0, const float* __restrict__ cw,
                             unsigned char* __restrict__ dst) {
    int row = blockIdx.x;                       // 20224
    int q   = threadIdx.x * 4;
    int k   = kperm(q);
    float4 v = {0.f, 0.f, 0.f, 0.f};
    if (row < 20000)      v = *(const float4*)(w0 + (size_t)row * 1024 + k);
    else if (row < 20003) v = *(const float4*)(cw + (size_t)(row - 20000) * 1024 + k);
    int p = __builtin_amdgcn_cvt_pk_fp8_f32(v.x, v.y, 0, false);
    p     = __builtin_amdgcn_cvt_pk_fp8_f32(v.z, v.w, p, true);
    *(int*)(dst + (size_t)row * 1024 + q) = p;
}

__global__ void cast_t1_w8(const float* __restrict__ w1, unsigned char* __restrict__ dst) {
    int row = blockIdx.x;                       // 10240
    if (threadIdx.x >= 64) return;
    int q = threadIdx.x * 4;
    int k = kperm(q);
    float4 v = {0.f, 0.f, 0.f, 0.f};
    if (row < 10000) v = *(const float4*)(w1 + (size_t)row * 256 + k);
    int p = __builtin_amdgcn_cvt_pk_fp8_f32(v.x, v.y, 0, false);
    p     = __builtin_amdgcn_cvt_pk_fp8_f32(v.z, v.w, p, true);
    *(int*)(dst + (size_t)row * 256 + q) = p;
}

__global__ void cast_A8(const ushort* __restrict__ Hb, unsigned char* __restrict__ dst) {
    int row = blockIdx.x;                       // 4096
    for (int i = threadIdx.x; i < LDA8 / 4; i += 256) {
        int q = i * 4;
        int k = kperm(q);
        const ushort* s = Hb + (size_t)row * LDHB + k;
        int p = __builtin_amdgcn_cvt_pk_fp8_f32(bf2f(s[0]), bf2f(s[1]), 0, false);
        p     = __builtin_amdgcn_cvt_pk_fp8_f32(bf2f(s[2]), bf2f(s[3]), p, true);
        *(int*)(dst + (size_t)row * LDA8 + q) = p;
    }
}

// ---------------------------------------------------------------------------
// cast tail weight (bf16, tails 2/3): src [rows_real][kin] -> dst [rows_pad][KOUT]
// ---------------------------------------------------------------------------
template<int KOUT>
__global__ void cast_tail_w(const float* __restrict__ src, ushort* __restrict__ dst,
                            int rows_real, int kin, int rows_pad) {
    int idx = blockIdx.x * 256 + threadIdx.x;
    const int n = rows_pad * KOUT;
    if (idx >= n) return;
    int r = idx / KOUT, k = idx - r * KOUT;
    float v = (r < rows_real && k < kin) ? src[(size_t)r * kin + k] : 0.f;
    dst[idx] = f2bf(v);
}

// ---------------------------------------------------------------------------
// Proj GEMM: Hb[4096][1408] = hb @ pbT^T  (m97 128x128, bf16, unchanged)
// ---------------------------------------------------------------------------
__global__ __launch_bounds__(256) void proj_gemm_mfma(const ushort* __restrict__ A,
                                                      const ushort* __restrict__ B,
                                                      ushort* __restrict__ C) {
    __shared__ ushort As[128 * 32];
    __shared__ ushort Bs[128 * 32];
    const int t  = threadIdx.x;
    const int wv = t >> 6, l = t & 63, lr = l & 15, lh = l >> 4;
    const int wr = wv >> 1, wc = wv & 1;
    const int rb = blockIdx.x * 128, cb = blockIdx.y * 128;
    f32x4 acc[4][4] = {};
    for (int k0 = 0; k0 < DPROJ; k0 += 32) {
        __syncthreads();
        #pragma unroll
        for (int is = 0; is < 2; ++is) {
            int rr = (t >> 2) + is * 64;
            GLOAD16(A + (size_t)(rb + rr) * DPROJ + k0 + (t & 3) * 8,
                    (char*)As + wv * 1024 + is * 4096);
            GLOAD16(B + (size_t)(cb + rr) * DPROJ + k0 + (t & 3) * 8,
                    (char*)Bs + wv * 1024 + is * 4096);
        }
        __syncthreads();
        short8 af[4], bf[4];
        #pragma unroll
        for (int m = 0; m < 4; ++m)
            af[m] = *(const short8*)(As + (wr * 64 + m * 16 + lr) * 32 + lh * 8);
        #pragma unroll
        for (int n = 0; n < 4; ++n)
            bf[n] = *(const short8*)(Bs + (wc * 64 + n * 16 + lr) * 32 + lh * 8);
        #pragma unroll
        for (int m = 0; m < 4; ++m)
            #pragma unroll
            for (int n = 0; n < 4; ++n)
                acc[m][n] = __builtin_amdgcn_mfma_f32_16x16x32_bf16(af[m], bf[n], acc[m][n], 0, 0, 0);
    }
    #pragma unroll
    for (int m = 0; m < 4; ++m)
        #pragma unroll
        for (int n = 0; n < 4; ++n)
            #pragma unroll
            for (int r = 0; r < 4; ++r) {
                int rl = wr * 64 + m * 16 + lh * 4 + r;
                int cl = wc * 64 + n * 16 + lr;
                C[(size_t)(rb + rl) * LDHB + cb + cl] = f2bf(acc[m][n][r]);
            }
}

// ---------------------------------------------------------------------------
// FP8 128x128 m97-style GEMM + sum-exp. BK=128 bytes, 4 waves, 33 KB LDS,
// 4 blocks/CU (multi-block latency overlap). Swizzle byte ^= (row&7)<<4;
// source col pre-inverse-swizzled (rule #21). 64 MFMA between barrier pairs.
// ---------------------------------------------------------------------------
template<int K>
__global__ __launch_bounds__(256, 4) void gemm_sumexp_f8s(
        const unsigned char* __restrict__ A, int lda,
        const unsigned char* __restrict__ B,
        const float* __restrict__ bias, const float* __restrict__ biasx,
        int splitB, int vocab,
        float* __restrict__ partial, int nCB) {
    __shared__ char As[128 * 128];
    __shared__ char Bs[128 * 128];
    __shared__ float red[2][128];
    const int t  = threadIdx.x;
    const int wv = t >> 6, l = t & 63, lr = l & 15, lh = l >> 4;
    const int wr = wv >> 1, wc = wv & 1;
    const int rb = blockIdx.x * 128, cb = blockIdx.y * 128;
    const int jr  = t >> 3;                              // 0..31
    const int csw = (((l & 7) ^ (l >> 3)) << 4);         // pre-inverse-swizzled col

    f32x4 acc[4][4] = {};
    for (int kt = 0; kt < K / 128; ++kt) {
        const int k0 = kt * 128;
        __syncthreads();
        #pragma unroll
        for (int j = 0; j < 4; ++j) {
            int rr = j * 32 + jr;
            GLOAD16(A + (size_t)(rb + rr) * lda + k0 + csw, As + j * 4096 + wv * 1024);
            GLOAD16(B + (size_t)(cb + rr) * K  + k0 + csw, Bs + j * 4096 + wv * 1024);
        }
        __syncthreads();
        long a8[4][4];
        #pragma unroll
        for (int m = 0; m < 4; ++m) {
            int row = wr * 64 + m * 16 + lr;
            #pragma unroll
            for (int s = 0; s < 2; ++s) {
                i64x2 v = *(const i64x2*)(As + row * 128 + ((lh * 32 + s * 16) ^ ((row & 7) << 4)));
                a8[m][s * 2] = v.x; a8[m][s * 2 + 1] = v.y;
            }
        }
        #pragma unroll
        for (int n = 0; n < 4; ++n) {
            long b8[4];
            int row = wc * 64 + n * 16 + lr;
            #pragma unroll
            for (int s = 0; s < 2; ++s) {
                i64x2 v = *(const i64x2*)(Bs + row * 128 + ((lh * 32 + s * 16) ^ ((row & 7) << 4)));
                b8[s * 2] = v.x; b8[s * 2 + 1] = v.y;
            }
            #pragma unroll
            for (int m = 0; m < 4; ++m)
                #pragma unroll
                for (int s4 = 0; s4 < 4; ++s4)
                    acc[m][n] = __builtin_amdgcn_mfma_f32_16x16x32_fp8_fp8(
                        a8[m][s4], b8[s4], acc[m][n], 0, 0, 0);
        }
    }
    // epilogue: exp(logit + bias), per-row partial over this 128-col block
    float rs[4][4];
    #pragma unroll
    for (int m = 0; m < 4; ++m)
        #pragma unroll
        for (int r = 0; r < 4; ++r) {
            float s = 0.f;
            #pragma unroll
            for (int n = 0; n < 4; ++n) {
                int col = cb + wc * 64 + n * 16 + lr;
                if (col < vocab) {
                    float bv = (col < splitB) ? bias[col] : biasx[col - splitB];
                    s += expf(acc[m][n][r] + bv);
                }
            }
            rs[m][r] = s;
        }
    #pragma unroll
    for (int m = 0; m < 4; ++m)
        #pragma unroll
        for (int r = 0; r < 4; ++r) {
            #pragma unroll
            for (int off = 1; off < 16; off <<= 1)
                rs[m][r] += __shfl_xor(rs[m][r], off);
            if (lr == 0) red[wc][wr * 64 + m * 16 + lh * 4 + r] = rs[m][r];
        }
    __syncthreads();
    if (t < 128)
        partial[(size_t)(rb + t) * nCB + blockIdx.y] = red[0][t] + red[1][t];
}

// ---------------------------------------------------------------------------
// 128x128 m97-style bf16 GEMM + sum-exp (tails 2,3)
// ---------------------------------------------------------------------------
template<int K>
__global__ __launch_bounds__(256) void gemm_sumexp_bf(
        const ushort* __restrict__ A,
        const ushort* __restrict__ B,
        const float* __restrict__ bias,
        int vocab, float* __restrict__ partial, int nCB) {
    __shared__ ushort As[128 * 32];
    __shared__ ushort Bs[128 * 32];
    __shared__ float  red[2][128];
    const int t  = threadIdx.x;
    const int wv = t >> 6, l = t & 63, lr = l & 15, lh = l >> 4;
    const int wr = wv >> 1, wc = wv & 1;
    const int rb = blockIdx.x * 128, cb = blockIdx.y * 128;
    f32x4 acc[4][4] = {};
    for (int k0 = 0; k0 < K; k0 += 32) {
        __syncthreads();
        #pragma unroll
        for (int is = 0; is < 2; ++is) {
            int rr = (t >> 2) + is * 64;
            GLOAD16(A + (size_t)(rb + rr) * LDHB + k0 + (t & 3) * 8,
                    (char*)As + wv * 1024 + is * 4096);
            GLOAD16(B + (size_t)(cb + rr) * K + k0 + (t & 3) * 8,
                    (char*)Bs + wv * 1024 + is * 4096);
        }
        __syncthreads();
        short8 af[4], bf[4];
        #pragma unroll
        for (int m = 0; m < 4; ++m)
            af[m] = *(const short8*)(As + (wr * 64 + m * 16 + lr) * 32 + lh * 8);
        #pragma unroll
        for (int n = 0; n < 4; ++n)
            bf[n] = *(const short8*)(Bs + (wc * 64 + n * 16 + lr) * 32 + lh * 8);
        #pragma unroll
        for (int m = 0; m < 4; ++m)
            #pragma unroll
            for (int n = 0; n < 4; ++n)
                acc[m][n] = __builtin_amdgcn_mfma_f32_16x16x32_bf16(af[m], bf[n], acc[m][n], 0, 0, 0);
    }
    float rs[4][4];
    #pragma unroll
    for (int m = 0; m < 4; ++m)
        #pragma unroll
        for (int r = 0; r < 4; ++r) {
            float s = 0.f;
            #pragma unroll
            for (int n = 0; n < 4; ++n) {
                int col = cb + wc * 64 + n * 16 + lr;
                if (col < vocab) s += expf(acc[m][n][r] + bias[col]);
            }
            rs[m][r] = s;
        }
    #pragma unroll
    for (int m = 0; m < 4; ++m)
        #pragma unroll
        for (int r = 0; r < 4; ++r) {
            #pragma unroll
            for (int off = 1; off < 16; off <<= 1)
                rs[m][r] += __shfl_xor(rs[m][r], off);
            if (lr == 0) red[wc][wr * 64 + m * 16 + lh * 4 + r] = rs[m][r];
        }
    __syncthreads();
    if (t < 128)
        partial[(size_t)(rb + t) * nCB + blockIdx.y] = red[0][t] + red[1][t];
}

// ---------------------------------------------------------------------------
// Finalize: one wave per row — gather target/cluster logits (fp32), assemble NLL.
// ---------------------------------------------------------------------------
__global__ void pals_finalize(const ushort* __restrict__ Hb,
                              const int* __restrict__ target,
                              const float* __restrict__ w0, const float* __restrict__ b0,
                              const float* __restrict__ w1, const float* __restrict__ b1,
                              const float* __restrict__ w2, const float* __restrict__ b2,
                              const float* __restrict__ w3, const float* __restrict__ b3,
                              const float* __restrict__ cw, const float* __restrict__ cbv,
                              const float* __restrict__ pH,
                              const float* __restrict__ pT1,
                              const float* __restrict__ pT2,
                              const float* __restrict__ pT3,
                              float* __restrict__ out) {
    const int wave = threadIdx.x >> 6;
    const int lane = threadIdx.x & 63;
    const int row  = blockIdx.x * 4 + wave;
    if (row >= NROW) return;
    const int t = target[row];
    const ushort* Hrow = Hb + (size_t)row * LDHB;

    float s = 0.f;
    for (int c = lane; c < NBH; c += 64) s += pH[(size_t)row * NBH + c];
    #pragma unroll
    for (int off = 32; off; off >>= 1) s += __shfl_xor(s, off);
    const float logSh = logf(s);

    float nll;
    if (t < 20000) {
        const float* wr0 = w0 + (size_t)t * 1024;
        float d = 0.f;
        for (int k = lane * 4; k < 1024; k += 256) {
            ushort4 a = *(const ushort4*)(Hrow + k);
            float4  b = *(const float4*)(wr0 + k);
            d += bf2f(a.x) * b.x + bf2f(a.y) * b.y + bf2f(a.z) * b.z + bf2f(a.w) * b.w;
        }
        #pragma unroll
        for (int off = 32; off; off >>= 1) d += __shfl_xor(d, off);
        nll = -(d + b0[t] - logSh);
    } else {
        const int i  = (t - 20000) / 10000 + 1;        // 1..3
        const int ci = 3 - i;                           // head_lp[:, -i] quirk
        const float* cwr = cw + (size_t)ci * 1024;
        float d = 0.f;
        for (int k = lane * 4; k < 1024; k += 256) {
            ushort4 a = *(const ushort4*)(Hrow + k);
            float4  b = *(const float4*)(cwr + k);
            d += bf2f(a.x) * b.x + bf2f(a.y) * b.y + bf2f(a.z) * b.z + bf2f(a.w) * b.w;
        }
        #pragma unroll
        for (int off = 32; off; off >>= 1) d += __shfl_xor(d, off);
        const float logit_c = d + cbv[ci];

        const int dl   = 1024 >> (2 * i);               // 256, 64, 16
        const int hoff = (i == 1) ? 1024 : (i == 2) ? 1280 : 1344;
        const float* wi = (i == 1) ? w1 : (i == 2) ? w2 : w3;
        const float* bi = (i == 1) ? b1 : (i == 2) ? b2 : b3;
        const float* pT = (i == 1) ? pT1 : (i == 2) ? pT2 : pT3;
        const int nbi  = (i == 1) ? NBT1 : NBT;
        const int tt = t - (20000 + (i - 1) * 10000);

        float dt = 0.f;
        const ushort* Hi = Hrow + hoff;
        for (int k = lane; k < dl; k += 64) dt += bf2f(Hi[k]) * wi[(size_t)tt * dl + k];
        #pragma unroll
        for (int off = 32; off; off >>= 1) dt += __shfl_xor(dt, off);

        float st = 0.f;
        for (int c = lane; c < nbi; c += 64) st += pT[(size_t)row * nbi + c];
        #pragma unroll
        for (int off = 32; off; off >>= 1) st += __shfl_xor(st, off);

        nll = -((logit_c - logSh) + (dt + bi[tt] - logf(st)));
    }
    if (lane == 0) out[row] = nll;
}

// ---------------------------------------------------------------------------
extern "C" void kernel_launch(void* const* d_in, const int* in_sizes, int n_in,
                              void* d_out, int out_size, void* d_ws, size_t ws_size,
                              hipStream_t stream) {
    const float* hidden = (const float*)d_in[0];
    const int*   target = (const int*)  d_in[1];
    const float* proj0  = (const float*)d_in[2];
    const float* w0     = (const float*)d_in[3];
    const float* b0     = (const float*)d_in[4];
    const float* proj1  = (const float*)d_in[5];
    const float* w1     = (const float*)d_in[6];
    const float* b1     = (const float*)d_in[7];
    const float* proj2  = (const float*)d_in[8];
    const float* w2     = (const float*)d_in[9];
    const float* b2     = (const float*)d_in[10];
    const float* proj3  = (const float*)d_in[11];
    const float* w3     = (const float*)d_in[12];
    const float* b3     = (const float*)d_in[13];
    const float* cw     = (const float*)d_in[14];
    const float* cbv    = (const float*)d_in[15];

    ushort* hb  = (ushort*)d_ws;                         // [4096][1024]
    ushort* pbT = hb  + (size_t)NROW * DPROJ;            // [1408][1024]
    ushort* Hb  = pbT + (size_t)LDHB * DPROJ;            // [4096][1408]
    ushort* WT2 = Hb  + (size_t)NROW * LDHB;             // [10112][64]
    ushort* WT3 = WT2 + (size_t)TAIL_VP * 64;            // [10112][32]
    unsigned char* WH8  = (unsigned char*)(WT3 + (size_t)TAIL_VP * 32);  // [20224][1024]
    unsigned char* WT18 = WH8  + (size_t)HEAD_VP * 1024;                 // [10240][256]
    unsigned char* A8   = WT18 + (size_t)TAIL1_P * 256;                  // [4096][1280]
    float*  pH  = (float*)(A8 + (size_t)NROW * LDA8);    // [4096][158]
    float*  pT1 = pH  + (size_t)NROW * NBH;              // [4096][80]
    float*  pT2 = pT1 + (size_t)NROW * NBT1;             // [4096][79]
    float*  pT3 = pT2 + (size_t)NROW * NBT;              // [4096][79]

    dim3 blk(256);
    cast_hidden_k<<<dim3(NROW * DPROJ / 1024), blk, 0, stream>>>(hidden, hb);
    cast_transpose_proj<<<dim3(16, 22), blk, 0, stream>>>(proj0, proj1, proj2, proj3, pbT);
    cast_head_w8<<<dim3(HEAD_VP), blk, 0, stream>>>(w0, cw, WH8);
    cast_t1_w8<<<dim3(TAIL1_P), blk, 0, stream>>>(w1, WT18);
    cast_tail_w<64><<<dim3((TAIL_VP * 64 + 255) / 256), blk, 0, stream>>>(w2, WT2, TAIL_V, 64, TAIL_VP);
    cast_tail_w<32><<<dim3((TAIL_VP * 32 + 255) / 256), blk, 0, stream>>>(w3, WT3, TAIL_V, 16, TAIL_VP);

    proj_gemm_mfma<<<dim3(32, 11), blk, 0, stream>>>(hb, pbT, Hb);
    cast_A8<<<dim3(NROW), blk, 0, stream>>>(Hb, A8);

    // head: 32 x 158 grid, fp8 128-tile, 4 blocks/CU
    gemm_sumexp_f8s<1024><<<dim3(32, NBH), blk, 0, stream>>>(
        A8, LDA8, WH8, b0, cbv, 20000, HEAD_V, pH, NBH);
    // tail1: 32 x 80, fp8 (A base offset 1024 bytes into A8 rows)
    gemm_sumexp_f8s<256><<<dim3(32, NBT1), blk, 0, stream>>>(
        A8 + 1024, LDA8, WT18, b1, b1, TAIL_V, TAIL_V, pT1, NBT1);
    // tails 2,3 on the 128-tile bf16 kernel
    gemm_sumexp_bf<64><<<dim3(32, NBT), blk, 0, stream>>>(
        Hb + 1280, WT2, b2, TAIL_V, pT2, NBT);
    gemm_sumexp_bf<32><<<dim3(32, NBT), blk, 0, stream>>>(
        Hb + 1344, WT3, b3, TAIL_V, pT3, NBT);

    pals_finalize<<<dim3(NROW / 4), blk, 0, stream>>>(
        Hb, target, w0, b0, w1, b1, w2, b2, w3, b3, cw, cbv,
        pH, pT1, pT2, pT3, (float*)d_out);
}

// Round 9
// 323.982 us; speedup vs baseline: 1.8514x; 1.2119x over previous
//
#include <hip/hip_runtime.h>
#include <hip/hip_bf16.h>
#include <math.h>

// Problem sizes (fixed)
#define NROW    4096
#define DPROJ   1024
#define LDHB    1408         // Hb row stride (bf16 elems)
#define LDA8    1536         // A8 row stride (bytes): 1024 head | 256 t1 | 128 t2 | 128 t3
#define HEAD_V  20003
#define TAIL_V  10000
#define HEAD_VP 20224        // 158*128
#define TAIL1_P 10240        // 80*128
#define TAIL_VP 10112        // 79*128
#define NBH     158
#define NBT1    80
#define NBT     79

// cast_all block ranges
#define CB_H    4096                 // hidden cast
#define CB_P    (CB_H + 352)         // transpose proj
#define CB_W0   (CB_P + 20224)       // head w fp8
#define CB_W1   (CB_W0 + 2560)       // tail1 w fp8 (4 rows/block)
#define CB_W2   (CB_W1 + 1264)       // tail2 w fp8 (8 rows/block)
#define CB_W3   (CB_W2 + 1264)       // tail3 w fp8 (8 rows/block)

typedef short short8 __attribute__((ext_vector_type(8)));
typedef float f32x4  __attribute__((ext_vector_type(4)));
typedef long  i64x2  __attribute__((ext_vector_type(2)));

__device__ __forceinline__ ushort f2bf(float f) {           // RNE f32 -> bf16
    unsigned u = __builtin_bit_cast(unsigned, f);
    return (ushort)((u + 0x7FFFu + ((u >> 16) & 1u)) >> 16);
}
__device__ __forceinline__ float bf2f(ushort u) {
    unsigned x = (unsigned)u << 16;
    return __builtin_bit_cast(float, x);
}
// within-128 K permutation (involution: swaps byte-addr bit-pairs [6:5]<->[4:3])
__device__ __forceinline__ int kperm(int q) {
    int q7 = q & 127;
    return (q & ~127) + ((q7 >> 3) & 3) * 32 + ((q7 >> 5) << 3) + (q7 & 7);
}

#define GLOAD16(gp, lp) __builtin_amdgcn_global_load_lds(                     \
    (const __attribute__((address_space(1))) void*)(gp),                      \
    (__attribute__((address_space(3))) void*)(lp), 16, 0, 0)

// ---------------------------------------------------------------------------
// cast_all: one launch, range-dispatched on blockIdx.x
//   [0,CB_H):    hidden f32 -> hb bf16
//   [CB_H,CB_P): proj concat transpose-cast -> pbT bf16
//   [CB_P,CB_W0): w0+cluster_w -> WH8 fp8 (kperm)
//   [CB_W0,CB_W1): w1 -> WT18 fp8 (kperm), 4 rows/block
//   [CB_W1,CB_W2): w2 -> WT28 fp8 (kperm, K 64->128 zero-pad), 8 rows/block
//   [CB_W2,CB_W3): w3 -> WT38 fp8 (kperm, K 16->128 zero-pad), 8 rows/block
// ---------------------------------------------------------------------------
__global__ void cast_all(const float* __restrict__ hidden,
                         const float* __restrict__ p0, const float* __restrict__ p1,
                         const float* __restrict__ p2, const float* __restrict__ p3,
                         const float* __restrict__ w0, const float* __restrict__ cw,
                         const float* __restrict__ w1, const float* __restrict__ w2,
                         const float* __restrict__ w3,
                         ushort* __restrict__ hb, ushort* __restrict__ pbT,
                         unsigned char* __restrict__ WH8, unsigned char* __restrict__ WT18,
                         unsigned char* __restrict__ WT28, unsigned char* __restrict__ WT38) {
    const int b = blockIdx.x;
    const int t = threadIdx.x;
    if (b < CB_H) {
        int i = (b * 256 + t) * 4;
        float4 v = *(const float4*)(hidden + i);
        ushort4 o = {f2bf(v.x), f2bf(v.y), f2bf(v.z), f2bf(v.w)};
        *(ushort4*)(hb + i) = o;
    } else if (b < CB_P) {
        __shared__ float tile[64][65];
        int r  = b - CB_H;
        int kb = (r & 15) * 64;
        int cb = (r >> 4) * 64;
        for (int p = 0; p < 4; ++p) {
            int kl = p * 16 + (t >> 4);
            int c4 = (t & 15) * 4;
            int k  = kb + kl;
            for (int j = 0; j < 4; ++j) {
                int c = cb + c4 + j;
                float v = 0.f;
                if      (c < 1024) v = p0[(size_t)k * 1024 + c];
                else if (c < 1280) v = p1[(size_t)k * 256  + (c - 1024)];
                else if (c < 1344) v = p2[(size_t)k * 64   + (c - 1280)];
                else if (c < 1360) v = p3[(size_t)k * 16   + (c - 1344)];
                tile[kl][c4 + j] = v;
            }
        }
        __syncthreads();
        for (int p = 0; p < 4; ++p) {
            int cl = p * 16 + (t >> 4);
            int k4 = (t & 15) * 4;
            ushort4 o = {f2bf(tile[k4 + 0][cl]), f2bf(tile[k4 + 1][cl]),
                         f2bf(tile[k4 + 2][cl]), f2bf(tile[k4 + 3][cl])};
            *(ushort4*)(pbT + (size_t)(cb + cl) * 1024 + kb + k4) = o;
        }
    } else if (b < CB_W0) {
        int row = b - CB_P;
        int q   = t * 4;
        int k   = kperm(q);
        float4 v = {0.f, 0.f, 0.f, 0.f};
        if (row < 20000)      v = *(const float4*)(w0 + (size_t)row * 1024 + k);
        else if (row < 20003) v = *(const float4*)(cw + (size_t)(row - 20000) * 1024 + k);
        int p = __builtin_amdgcn_cvt_pk_fp8_f32(v.x, v.y, 0, false);
        p     = __builtin_amdgcn_cvt_pk_fp8_f32(v.z, v.w, p, true);
        *(int*)(WH8 + (size_t)row * 1024 + q) = p;
    } else if (b < CB_W1) {
        int row  = (b - CB_W0) * 4 + (t >> 6);
        int q    = (t & 63) * 4;
        int k    = kperm(q);
        float4 v = {0.f, 0.f, 0.f, 0.f};
        if (row < 10000) v = *(const float4*)(w1 + (size_t)row * 256 + k);
        int p = __builtin_amdgcn_cvt_pk_fp8_f32(v.x, v.y, 0, false);
        p     = __builtin_amdgcn_cvt_pk_fp8_f32(v.z, v.w, p, true);
        *(int*)(WT18 + (size_t)row * 256 + q) = p;
    } else if (b < CB_W2) {
        int row = (b - CB_W1) * 8 + (t >> 5);
        int q   = (t & 31) * 4;
        int k   = kperm(q);                          // 0..127
        float4 v = {0.f, 0.f, 0.f, 0.f};
        if (row < 10000 && k < 64) v = *(const float4*)(w2 + (size_t)row * 64 + k);
        int p = __builtin_amdgcn_cvt_pk_fp8_f32(v.x, v.y, 0, false);
        p     = __builtin_amdgcn_cvt_pk_fp8_f32(v.z, v.w, p, true);
        *(int*)(WT28 + (size_t)row * 128 + q) = p;
    } else {
        int row = (b - CB_W2) * 8 + (t >> 5);
        int q   = (t & 31) * 4;
        int k   = kperm(q);
        float4 v = {0.f, 0.f, 0.f, 0.f};
        if (row < 10000 && k < 16) v = *(const float4*)(w3 + (size_t)row * 16 + k);
        int p = __builtin_amdgcn_cvt_pk_fp8_f32(v.x, v.y, 0, false);
        p     = __builtin_amdgcn_cvt_pk_fp8_f32(v.z, v.w, p, true);
        *(int*)(WT38 + (size_t)row * 128 + q) = p;
    }
}

// ---------------------------------------------------------------------------
// cast_A8: Hb bf16 -> A8 fp8, K-permuted, 1536 B/row
//   bytes [0,1280):  H cols [0,1280) (head + tail1)
//   bytes [1280,1408): H cols [1280,1344) real, rest zero  (tail2)
//   bytes [1408,1536): H cols [1344,1360) real, rest zero  (tail3)
// ---------------------------------------------------------------------------
__global__ void cast_A8(const ushort* __restrict__ Hb, unsigned char* __restrict__ dst) {
    int row = blockIdx.x;
    for (int i = threadIdx.x; i < LDA8 / 4; i += 256) {
        int q = i * 4;
        int k = kperm(q);
        float4 v = {0.f, 0.f, 0.f, 0.f};
        const ushort* s = nullptr;
        if (k < 1344)      s = Hb + (size_t)row * LDHB + k;
        else if (k >= 1408 && k < 1424) s = Hb + (size_t)row * LDHB + 1344 + (k - 1408);
        if (s) { v.x = bf2f(s[0]); v.y = bf2f(s[1]); v.z = bf2f(s[2]); v.w = bf2f(s[3]); }
        int p = __builtin_amdgcn_cvt_pk_fp8_f32(v.x, v.y, 0, false);
        p     = __builtin_amdgcn_cvt_pk_fp8_f32(v.z, v.w, p, true);
        *(int*)(dst + (size_t)row * LDA8 + q) = p;
    }
}

// ---------------------------------------------------------------------------
// Proj GEMM: Hb[4096][1408] = hb @ pbT^T  (m97 128x128, bf16)
// ---------------------------------------------------------------------------
__global__ __launch_bounds__(256) void proj_gemm_mfma(const ushort* __restrict__ A,
                                                      const ushort* __restrict__ B,
                                                      ushort* __restrict__ C) {
    __shared__ ushort As[128 * 32];
    __shared__ ushort Bs[128 * 32];
    const int t  = threadIdx.x;
    const int wv = t >> 6, l = t & 63, lr = l & 15, lh = l >> 4;
    const int wr = wv >> 1, wc = wv & 1;
    const int rb = blockIdx.x * 128, cb = blockIdx.y * 128;
    f32x4 acc[4][4] = {};
    for (int k0 = 0; k0 < DPROJ; k0 += 32) {
        __syncthreads();
        #pragma unroll
        for (int is = 0; is < 2; ++is) {
            int rr = (t >> 2) + is * 64;
            GLOAD16(A + (size_t)(rb + rr) * DPROJ + k0 + (t & 3) * 8,
                    (char*)As + wv * 1024 + is * 4096);
            GLOAD16(B + (size_t)(cb + rr) * DPROJ + k0 + (t & 3) * 8,
                    (char*)Bs + wv * 1024 + is * 4096);
        }
        __syncthreads();
        short8 af[4], bf[4];
        #pragma unroll
        for (int m = 0; m < 4; ++m)
            af[m] = *(const short8*)(As + (wr * 64 + m * 16 + lr) * 32 + lh * 8);
        #pragma unroll
        for (int n = 0; n < 4; ++n)
            bf[n] = *(const short8*)(Bs + (wc * 64 + n * 16 + lr) * 32 + lh * 8);
        #pragma unroll
        for (int m = 0; m < 4; ++m)
            #pragma unroll
            for (int n = 0; n < 4; ++n)
                acc[m][n] = __builtin_amdgcn_mfma_f32_16x16x32_bf16(af[m], bf[n], acc[m][n], 0, 0, 0);
    }
    #pragma unroll
    for (int m = 0; m < 4; ++m)
        #pragma unroll
        for (int n = 0; n < 4; ++n)
            #pragma unroll
            for (int r = 0; r < 4; ++r) {
                int rl = wr * 64 + m * 16 + lh * 4 + r;
                int cl = wc * 64 + n * 16 + lr;
                C[(size_t)(rb + rl) * LDHB + cb + cl] = f2bf(acc[m][n][r]);
            }
}

// ---------------------------------------------------------------------------
// Unified FP8 128x128 GEMM + sum-exp, all 4 logits clusters in one launch.
// Segment selected by blockIdx.y. BK=128 B, 4 waves, 33 KB LDS, 4 blocks/CU.
// Swizzle byte ^= (row&7)<<4; source pre-inverse-swizzled (rule #21).
// ---------------------------------------------------------------------------
__global__ __launch_bounds__(256, 4) void gemm_sumexp_all(
        const unsigned char* __restrict__ A8,
        const unsigned char* __restrict__ WH8, const unsigned char* __restrict__ WT18,
        const unsigned char* __restrict__ WT28, const unsigned char* __restrict__ WT38,
        const float* __restrict__ b0, const float* __restrict__ cbv,
        const float* __restrict__ b1, const float* __restrict__ b2,
        const float* __restrict__ b3,
        float* __restrict__ pH, float* __restrict__ pT1,
        float* __restrict__ pT2, float* __restrict__ pT3) {
    const int y = blockIdx.y;
    const unsigned char* B;
    const float *bias, *biasx;
    float* partial;
    int aoff, K, splitB, vocab, nCB, cbY;
    if (y < NBH) {
        B = WH8;  bias = b0; biasx = cbv; partial = pH;
        aoff = 0;    K = 1024; splitB = 20000;  vocab = HEAD_V; nCB = NBH;  cbY = y;
    } else if (y < NBH + NBT1) {
        B = WT18; bias = b1; biasx = b1; partial = pT1;
        aoff = 1024; K = 256;  splitB = TAIL_V; vocab = TAIL_V; nCB = NBT1; cbY = y - NBH;
    } else if (y < NBH + NBT1 + NBT) {
        B = WT28; bias = b2; biasx = b2; partial = pT2;
        aoff = 1280; K = 128;  splitB = TAIL_V; vocab = TAIL_V; nCB = NBT;  cbY = y - NBH - NBT1;
    } else {
        B = WT38; bias = b3; biasx = b3; partial = pT3;
        aoff = 1408; K = 128;  splitB = TAIL_V; vocab = TAIL_V; nCB = NBT;  cbY = y - NBH - NBT1 - NBT;
    }

    __shared__ char As[128 * 128];
    __shared__ char Bs[128 * 128];
    __shared__ float red[2][128];
    const int t  = threadIdx.x;
    const int wv = t >> 6, l = t & 63, lr = l & 15, lh = l >> 4;
    const int wr = wv >> 1, wc = wv & 1;
    const int rb = blockIdx.x * 128, cb = cbY * 128;
    const int jr  = t >> 3;
    const int csw = (((l & 7) ^ (l >> 3)) << 4);

    const unsigned char* Ab = A8 + aoff;
    f32x4 acc[4][4] = {};
    const int kNT = K >> 7;
    for (int kt = 0; kt < kNT; ++kt) {
        const int k0 = kt * 128;
        __syncthreads();
        #pragma unroll
        for (int j = 0; j < 4; ++j) {
            int rr = j * 32 + jr;
            GLOAD16(Ab + (size_t)(rb + rr) * LDA8 + k0 + csw, As + j * 4096 + wv * 1024);
            GLOAD16(B  + (size_t)(cb + rr) * K    + k0 + csw, Bs + j * 4096 + wv * 1024);
        }
        __syncthreads();
        long a8[4][4];
        #pragma unroll
        for (int m = 0; m < 4; ++m) {
            int row = wr * 64 + m * 16 + lr;
            #pragma unroll
            for (int s = 0; s < 2; ++s) {
                i64x2 v = *(const i64x2*)(As + row * 128 + ((lh * 32 + s * 16) ^ ((row & 7) << 4)));
                a8[m][s * 2] = v.x; a8[m][s * 2 + 1] = v.y;
            }
        }
        #pragma unroll
        for (int n = 0; n < 4; ++n) {
            long b8[4];
            int row = wc * 64 + n * 16 + lr;
            #pragma unroll
            for (int s = 0; s < 2; ++s) {
                i64x2 v = *(const i64x2*)(Bs + row * 128 + ((lh * 32 + s * 16) ^ ((row & 7) << 4)));
                b8[s * 2] = v.x; b8[s * 2 + 1] = v.y;
            }
            #pragma unroll
            for (int m = 0; m < 4; ++m)
                #pragma unroll
                for (int s4 = 0; s4 < 4; ++s4)
                    acc[m][n] = __builtin_amdgcn_mfma_f32_16x16x32_fp8_fp8(
                        a8[m][s4], b8[s4], acc[m][n], 0, 0, 0);
        }
    }
    // epilogue: exp(logit + bias), per-row partial over this 128-col block
    float rs[4][4];
    #pragma unroll
    for (int m = 0; m < 4; ++m)
        #pragma unroll
        for (int r = 0; r < 4; ++r) {
            float s = 0.f;
            #pragma unroll
            for (int n = 0; n < 4; ++n) {
                int col = cb + wc * 64 + n * 16 + lr;
                if (col < vocab) {
                    float bv = (col < splitB) ? bias[col] : biasx[col - splitB];
                    s += expf(acc[m][n][r] + bv);
                }
            }
            rs[m][r] = s;
        }
    #pragma unroll
    for (int m = 0; m < 4; ++m)
        #pragma unroll
        for (int r = 0; r < 4; ++r) {
            #pragma unroll
            for (int off = 1; off < 16; off <<= 1)
                rs[m][r] += __shfl_xor(rs[m][r], off);
            if (lr == 0) red[wc][wr * 64 + m * 16 + lh * 4 + r] = rs[m][r];
        }
    __syncthreads();
    if (t < 128)
        partial[(size_t)(rb + t) * nCB + cbY] = red[0][t] + red[1][t];
}

// ---------------------------------------------------------------------------
// Finalize: one wave per row — gather target/cluster logits (fp32), assemble NLL.
// ---------------------------------------------------------------------------
__global__ void pals_finalize(const ushort* __restrict__ Hb,
                              const int* __restrict__ target,
                              const float* __restrict__ w0, const float* __restrict__ b0,
                              const float* __restrict__ w1, const float* __restrict__ b1,
                              const float* __restrict__ w2, const float* __restrict__ b2,
                              const float* __restrict__ w3, const float* __restrict__ b3,
                              const float* __restrict__ cw, const float* __restrict__ cbv,
                              const float* __restrict__ pH,
                              const float* __restrict__ pT1,
                              const float* __restrict__ pT2,
                              const float* __restrict__ pT3,
                              float* __restrict__ out) {
    const int wave = threadIdx.x >> 6;
    const int lane = threadIdx.x & 63;
    const int row  = blockIdx.x * 4 + wave;
    if (row >= NROW) return;
    const int t = target[row];
    const ushort* Hrow = Hb + (size_t)row * LDHB;

    float s = 0.f;
    for (int c = lane; c < NBH; c += 64) s += pH[(size_t)row * NBH + c];
    #pragma unroll
    for (int off = 32; off; off >>= 1) s += __shfl_xor(s, off);
    const float logSh = logf(s);

    float nll;
    if (t < 20000) {
        const float* wr0 = w0 + (size_t)t * 1024;
        float d = 0.f;
        for (int k = lane * 4; k < 1024; k += 256) {
            ushort4 a = *(const ushort4*)(Hrow + k);
            float4  b = *(const float4*)(wr0 + k);
            d += bf2f(a.x) * b.x + bf2f(a.y) * b.y + bf2f(a.z) * b.z + bf2f(a.w) * b.w;
        }
        #pragma unroll
        for (int off = 32; off; off >>= 1) d += __shfl_xor(d, off);
        nll = -(d + b0[t] - logSh);
    } else {
        const int i  = (t - 20000) / 10000 + 1;        // 1..3
        const int ci = 3 - i;                           // head_lp[:, -i] quirk
        const float* cwr = cw + (size_t)ci * 1024;
        float d = 0.f;
        for (int k = lane * 4; k < 1024; k += 256) {
            ushort4 a = *(const ushort4*)(Hrow + k);
            float4  b = *(const float4*)(cwr + k);
            d += bf2f(a.x) * b.x + bf2f(a.y) * b.y + bf2f(a.z) * b.z + bf2f(a.w) * b.w;
        }
        #pragma unroll
        for (int off = 32; off; off >>= 1) d += __shfl_xor(d, off);
        const float logit_c = d + cbv[ci];

        const int dl   = 1024 >> (2 * i);               // 256, 64, 16
        const int hoff = (i == 1) ? 1024 : (i == 2) ? 1280 : 1344;
        const float* wi = (i == 1) ? w1 : (i == 2) ? w2 : w3;
        const float* bi = (i == 1) ? b1 : (i == 2) ? b2 : b3;
        const float* pT = (i == 1) ? pT1 : (i == 2) ? pT2 : pT3;
        const int nbi  = (i == 1) ? NBT1 : NBT;
        const int tt = t - (20000 + (i - 1) * 10000);

        float dt = 0.f;
        const ushort* Hi = Hrow + hoff;
        for (int k = lane; k < dl; k += 64) dt += bf2f(Hi[k]) * wi[(size_t)tt * dl + k];
        #pragma unroll
        for (int off = 32; off; off >>= 1) dt += __shfl_xor(dt, off);

        float st = 0.f;
        for (int c = lane; c < nbi; c += 64) st += pT[(size_t)row * nbi + c];
        #pragma unroll
        for (int off = 32; off; off >>= 1) st += __shfl_xor(st, off);

        nll = -((logit_c - logSh) + (dt + bi[tt] - logf(st)));
    }
    if (lane == 0) out[row] = nll;
}

// ---------------------------------------------------------------------------
extern "C" void kernel_launch(void* const* d_in, const int* in_sizes, int n_in,
                              void* d_out, int out_size, void* d_ws, size_t ws_size,
                              hipStream_t stream) {
    const float* hidden = (const float*)d_in[0];
    const int*   target = (const int*)  d_in[1];
    const float* proj0  = (const float*)d_in[2];
    const float* w0     = (const float*)d_in[3];
    const float* b0     = (const float*)d_in[4];
    const float* proj1  = (const float*)d_in[5];
    const float* w1     = (const float*)d_in[6];
    const float* b1     = (const float*)d_in[7];
    const float* proj2  = (const float*)d_in[8];
    const float* w2     = (const float*)d_in[9];
    const float* b2     = (const float*)d_in[10];
    const float* proj3  = (const float*)d_in[11];
    const float* w3     = (const float*)d_in[12];
    const float* b3     = (const float*)d_in[13];
    const float* cw     = (const float*)d_in[14];
    const float* cbv    = (const float*)d_in[15];

    ushort* hb  = (ushort*)d_ws;                         // [4096][1024]
    ushort* pbT = hb  + (size_t)NROW * DPROJ;            // [1408][1024]
    ushort* Hb  = pbT + (size_t)LDHB * DPROJ;            // [4096][1408]
    unsigned char* WH8  = (unsigned char*)(Hb + (size_t)NROW * LDHB);    // [20224][1024]
    unsigned char* WT18 = WH8  + (size_t)HEAD_VP * 1024;                 // [10240][256]
    unsigned char* WT28 = WT18 + (size_t)TAIL1_P * 256;                  // [10112][128]
    unsigned char* WT38 = WT28 + (size_t)TAIL_VP * 128;                  // [10112][128]
    unsigned char* A8   = WT38 + (size_t)TAIL_VP * 128;                  // [4096][1536]
    float*  pH  = (float*)(A8 + (size_t)NROW * LDA8);    // [4096][158]
    float*  pT1 = pH  + (size_t)NROW * NBH;              // [4096][80]
    float*  pT2 = pT1 + (size_t)NROW * NBT1;             // [4096][79]
    float*  pT3 = pT2 + (size_t)NROW * NBT;              // [4096][79]

    dim3 blk(256);
    cast_all<<<dim3(CB_W3), blk, 0, stream>>>(
        hidden, proj0, proj1, proj2, proj3, w0, cw, w1, w2, w3,
        hb, pbT, WH8, WT18, WT28, WT38);

    proj_gemm_mfma<<<dim3(32, 11), blk, 0, stream>>>(hb, pbT, Hb);
    cast_A8<<<dim3(NROW), blk, 0, stream>>>(Hb, A8);

    // all 4 logits GEMMs in one launch: 32 x 396 grid, 4 blocks/CU
    gemm_sumexp_all<<<dim3(32, NBH + NBT1 + NBT + NBT), blk, 0, stream>>>(
        A8, WH8, WT18, WT28, WT38, b0, cbv, b1, b2, b3, pH, pT1, pT2, pT3);

    pals_finalize<<<dim3(NROW / 4), blk, 0, stream>>>(
        Hb, target, w0, b0, w1, b1, w2, b2, w3, b3, cw, cbv,
        pH, pT1, pT2, pT3, (float*)d_out);
}